// Round 1
// baseline (811.556 us; speedup 1.0000x reference)
//
#include <hip/hip_runtime.h>
#include <hip/hip_bf16.h>

#define DIMC 256
#define STATE 128
#define RANK 64
#define NBATCH 16
#define LSEQ 4096
#define NROWS (NBATCH*LSEQ)   // 65536
#define LN_EPS 1e-5f

// ---------------- A = V @ U^T  (128x128) ----------------
__global__ __launch_bounds__(128) void a_kernel(const float* __restrict__ U, const float* __restrict__ V,
                                                float* __restrict__ A) {
    int i = blockIdx.x, j = threadIdx.x;
    float s = 0.f;
    #pragma unroll
    for (int r = 0; r < RANK; ++r) s += V[i*RANK + r] * U[j*RANK + r];
    A[i*STATE + j] = s;   // A[i][j]; h_new[j] = sum_i h[i]*A[i][j]
}

// ---------------- generic tiled fp32 GEMM: C = A @ Bw^T + bias ----------------
// AMODE 0: Asrc is x with layout [NBATCH][DIMC][LSEQ]; logical row = b*LSEQ+l, k = channel (K==DIMC)
// AMODE 1: Asrc is row-major M x K
template<int AMODE>
__global__ __launch_bounds__(256) void gemm64(const float* __restrict__ Asrc, const float* __restrict__ Bw,
                                              const float* __restrict__ bias, float* __restrict__ C,
                                              int M, int N, int K) {
    __shared__ float As[16*68];
    __shared__ float Bs[16*68];
    const int t = threadIdx.x;
    const int n0blk = blockIdx.x * 64;
    const int r0 = blockIdx.y * 64;
    const int tx = t & 15, ty = t >> 4;
    float acc[4][4] = {};
    for (int k0 = 0; k0 < K; k0 += 16) {
        if (AMODE == 0) {
            const int b = r0 / LSEQ, lbase = r0 % LSEQ;
            const int ll = t & 63;
            #pragma unroll
            for (int i = 0; i < 4; ++i) {
                int cl = i*4 + (t>>6);   // 0..15
                As[cl*68 + ll] = Asrc[((size_t)b*DIMC + (k0+cl))*LSEQ + lbase + ll];
            }
        } else {
            #pragma unroll
            for (int i = 0; i < 4; ++i) {
                int ml = i*16 + (t>>4);
                int kl = t & 15;
                As[kl*68 + ml] = Asrc[(size_t)(r0+ml)*K + k0 + kl];
            }
        }
        #pragma unroll
        for (int i = 0; i < 4; ++i) {
            int nl = i*16 + (t>>4);
            int kl = t & 15;
            Bs[kl*68 + nl] = Bw[(size_t)(n0blk+nl)*K + k0 + kl];
        }
        __syncthreads();
        #pragma unroll
        for (int k = 0; k < 16; ++k) {
            float4 a4 = *(const float4*)(As + k*68 + ty*4);
            float4 b4 = *(const float4*)(Bs + k*68 + tx*4);
            float av[4] = {a4.x, a4.y, a4.z, a4.w};
            float bv[4] = {b4.x, b4.y, b4.z, b4.w};
            #pragma unroll
            for (int i = 0; i < 4; ++i)
                #pragma unroll
                for (int j = 0; j < 4; ++j)
                    acc[i][j] += av[i] * bv[j];
        }
        __syncthreads();
    }
    #pragma unroll
    for (int i = 0; i < 4; ++i) {
        size_t row = (size_t)r0 + ty*4 + i;
        #pragma unroll
        for (int j = 0; j < 4; ++j) {
            int col = n0blk + tx*4 + j;
            C[row*(size_t)N + col] = acc[i][j] + bias[col];
        }
    }
}

// ---------------- block-local scan: h = h*A + bx_t, emit h ----------------
// grid (64 blocks_l, NBATCH, 2 dirs), 128 threads (one per state channel)
__global__ __launch_bounds__(128) void scan_kernel(const float* __restrict__ bx, const float* __restrict__ A,
                                                   float* __restrict__ ylr, float* __restrict__ yrl) {
    __shared__ __hip_bfloat16 Alds[STATE*STATE];
    __shared__ float h[STATE];
    const int t = threadIdx.x;
    const int blk = blockIdx.x;
    const int b = blockIdx.y;
    const int dir = blockIdx.z;
    for (int i = t; i < STATE*STATE; i += 128) Alds[i] = __float2bfloat16(A[i]);
    h[t] = 0.f;
    __syncthreads();
    float* yout = (dir == 0) ? ylr : yrl;
    for (int tt = 0; tt < 64; ++tt) {
        int lp = blk*64 + tt;                         // direction-local position
        int lorig = (dir == 0) ? lp : (LSEQ-1-lp);    // index into shared bx
        float s = bx[((size_t)b*LSEQ + lorig)*STATE + t];
        #pragma unroll 8
        for (int i = 0; i < STATE; ++i)
            s += h[i] * __bfloat162float(Alds[i*STATE + t]);
        __syncthreads();   // all reads of h done
        h[t] = s;
        yout[((size_t)b*LSEQ + lp)*STATE + t] = s;
        __syncthreads();   // h updated for next step
    }
}

// ---------------- conv7 + direction combine: u = 0.5*(ulr + url) + conv_b ----------------
__global__ __launch_bounds__(128) void conv_combine(const float* __restrict__ ylr, const float* __restrict__ yrl,
                                                    const float* __restrict__ conv_w, const float* __restrict__ conv_b,
                                                    float* __restrict__ u) {
    const int s = threadIdx.x;
    const int l = blockIdx.x;
    const int b = blockIdx.y;
    float w[7];
    #pragma unroll
    for (int i = 0; i < 7; ++i) w[i] = conv_w[s*7 + i];
    const float* plr = ylr + (size_t)b*LSEQ*STATE;
    const float* prl = yrl + (size_t)b*LSEQ*STATE;
    float acc = plr[(size_t)l*STATE + s];
    #pragma unroll
    for (int i = 0; i < 7; ++i) {
        int q = l - 3 + i;
        if (q >= 0 && q < LSEQ) acc += w[i] * plr[(size_t)q*STATE + s];
    }
    const int lp = LSEQ - 1 - l;   // rl stream position corresponding to original l
    acc += prl[(size_t)lp*STATE + s];
    #pragma unroll
    for (int i = 0; i < 7; ++i) {
        int q = lp - 3 + i;
        if (q >= 0 && q < LSEQ) acc += w[i] * prl[(size_t)q*STATE + s];
    }
    u[((size_t)b*LSEQ + l)*STATE + s] = 0.5f*acc + conv_b[s];
}

// ---------------- fused: gate GEMM + out GEMM + sigmoid*o + residual + LN + transposed write ----
// block: 32 rows (l) x 256 cols (c), 256 threads, micro-tile 4x8
__global__ __launch_bounds__(256) void fused_out(const float* __restrict__ x, const float* __restrict__ u,
    const float* __restrict__ out_w, const float* __restrict__ out_b,
    const float* __restrict__ gate_w, const float* __restrict__ gate_b,
    const float* __restrict__ norm_g, const float* __restrict__ norm_b,
    float* __restrict__ y) {
    __shared__ float smem[32*257];        // aliased: As(16*36) + Bs(16*260) during GEMM, vbuf after
    __shared__ float mus[32], rstds[32];
    float* As = smem;                     // 576 floats
    float* Bs = smem + 576;               // 4160 floats
    const int t = threadIdx.x;
    const int r0 = blockIdx.x * 32;
    const int b = r0 / LSEQ, l0 = r0 % LSEQ;
    const int tx = t & 31, ty = t >> 5;
    const int m0 = ty*4, n0 = tx*8;
    float accg[4][8] = {};
    float acco[4][8] = {};
    // gate GEMM: K = DIMC over x channels
    for (int k0 = 0; k0 < DIMC; k0 += 16) {
        {
            int ll = t & 31;
            #pragma unroll
            for (int i = 0; i < 2; ++i) {
                int cl = i*8 + (t>>5);
                As[cl*36 + ll] = x[((size_t)b*DIMC + k0 + cl)*LSEQ + l0 + ll];
            }
        }
        #pragma unroll
        for (int i = 0; i < 16; ++i) {
            int nl = i*16 + (t>>4), kl = t & 15;
            Bs[kl*260 + nl] = gate_w[(size_t)nl*DIMC + k0 + kl];
        }
        __syncthreads();
        #pragma unroll
        for (int k = 0; k < 16; ++k) {
            float4 a4 = *(const float4*)(As + k*36 + m0);
            float4 bl = *(const float4*)(Bs + k*260 + n0);
            float4 bh = *(const float4*)(Bs + k*260 + n0 + 4);
            float av[4] = {a4.x,a4.y,a4.z,a4.w};
            float bv[8] = {bl.x,bl.y,bl.z,bl.w,bh.x,bh.y,bh.z,bh.w};
            #pragma unroll
            for (int i = 0; i < 4; ++i)
                #pragma unroll
                for (int j = 0; j < 8; ++j)
                    accg[i][j] += av[i]*bv[j];
        }
        __syncthreads();
    }
    // out GEMM: K = STATE over u
    for (int k0 = 0; k0 < STATE; k0 += 16) {
        #pragma unroll
        for (int i = 0; i < 2; ++i) {
            int ml = i*16 + (t>>4), kl = t & 15;
            As[kl*36 + ml] = u[(size_t)(r0+ml)*STATE + k0 + kl];
        }
        #pragma unroll
        for (int i = 0; i < 16; ++i) {
            int nl = i*16 + (t>>4), kl = t & 15;
            Bs[kl*260 + nl] = out_w[(size_t)nl*STATE + k0 + kl];
        }
        __syncthreads();
        #pragma unroll
        for (int k = 0; k < 16; ++k) {
            float4 a4 = *(const float4*)(As + k*36 + m0);
            float4 bl = *(const float4*)(Bs + k*260 + n0);
            float4 bh = *(const float4*)(Bs + k*260 + n0 + 4);
            float av[4] = {a4.x,a4.y,a4.z,a4.w};
            float bv[8] = {bl.x,bl.y,bl.z,bl.w,bh.x,bh.y,bh.z,bh.w};
            #pragma unroll
            for (int i = 0; i < 4; ++i)
                #pragma unroll
                for (int j = 0; j < 8; ++j)
                    acco[i][j] += av[i]*bv[j];
        }
        __syncthreads();
    }
    // epilogue: v = sigmoid(gate)*o + residual
    float* vbuf = smem;   // 32 x 257
    #pragma unroll
    for (int i = 0; i < 4; ++i) {
        int l = l0 + m0 + i;
        #pragma unroll
        for (int j = 0; j < 8; ++j) {
            int c = n0 + j;
            float xval = x[((size_t)b*DIMC + c)*LSEQ + l];
            float g = 1.f/(1.f + expf(-(accg[i][j] + gate_b[c])));
            float o = acco[i][j] + out_b[c];
            vbuf[(m0+i)*257 + c] = g*o + xval;
        }
    }
    __syncthreads();
    // LayerNorm stats: 8 threads per row
    {
        int rr = t >> 3, lane8 = t & 7;
        float s1 = 0.f, s2 = 0.f;
        #pragma unroll
        for (int k = 0; k < 32; ++k) {
            float v = vbuf[rr*257 + lane8 + 8*k];
            s1 += v; s2 += v*v;
        }
        s1 += __shfl_xor(s1, 1); s2 += __shfl_xor(s2, 1);
        s1 += __shfl_xor(s1, 2); s2 += __shfl_xor(s2, 2);
        s1 += __shfl_xor(s1, 4); s2 += __shfl_xor(s2, 4);
        if (lane8 == 0) {
            float mu = s1 * (1.f/256.f);
            float var = s2 * (1.f/256.f) - mu*mu;
            mus[rr] = mu;
            rstds[rr] = rsqrtf(var + LN_EPS);
        }
    }
    __syncthreads();
    // transposed write: thread t = channel c, 32 consecutive l as 8x float4
    {
        int c = t;
        float g = norm_g[c], be = norm_b[c];
        float* outp = y + ((size_t)b*DIMC + c)*LSEQ + l0;
        #pragma unroll
        for (int q = 0; q < 8; ++q) {
            float4 v4;
            v4.x = (vbuf[(q*4+0)*257 + c] - mus[q*4+0]) * rstds[q*4+0] * g + be;
            v4.y = (vbuf[(q*4+1)*257 + c] - mus[q*4+1]) * rstds[q*4+1] * g + be;
            v4.z = (vbuf[(q*4+2)*257 + c] - mus[q*4+2]) * rstds[q*4+2] * g + be;
            v4.w = (vbuf[(q*4+3)*257 + c] - mus[q*4+3]) * rstds[q*4+3] * g + be;
            *(float4*)(outp + q*4) = v4;
        }
    }
}

extern "C" void kernel_launch(void* const* d_in, const int* in_sizes, int n_in,
                              void* d_out, int out_size, void* d_ws, size_t ws_size,
                              hipStream_t stream) {
    const float* x      = (const float*)d_in[0];
    const float* in_w   = (const float*)d_in[1];
    const float* in_b   = (const float*)d_in[2];
    const float* U      = (const float*)d_in[3];
    const float* V      = (const float*)d_in[4];
    const float* B_w    = (const float*)d_in[5];
    const float* B_b    = (const float*)d_in[6];
    const float* out_w  = (const float*)d_in[7];
    const float* out_b  = (const float*)d_in[8];
    const float* gate_w = (const float*)d_in[9];
    const float* gate_b = (const float*)d_in[10];
    const float* norm_g = (const float*)d_in[11];
    const float* norm_b = (const float*)d_in[12];
    const float* conv_w = (const float*)d_in[13];
    const float* conv_b = (const float*)d_in[14];

    float* yfinal = (float*)d_out;                                 // [16][256][64][64]
    float* state_out = yfinal + (size_t)NBATCH*DIMC*LSEQ;          // [16][4096][128] == x1 (lr)

    float* ws  = (float*)d_ws;
    float* bxu = ws;                                  // NROWS*STATE: bx, later reused as u
    float* Amat = ws + (size_t)NROWS*STATE;           // 128*128

    // scratch inside the y output region (overwritten by fused_out at the end):
    float* ylr = yfinal;                              // NROWS*STATE
    float* yrl = yfinal + (size_t)NROWS*STATE;        // NROWS*STATE

    a_kernel<<<dim3(STATE), dim3(STATE), 0, stream>>>(U, V, Amat);
    // x1 = seq @ in_proj_w^T + b  -> state_seq output (also B-GEMM input)
    gemm64<0><<<dim3(STATE/64, NROWS/64), dim3(256), 0, stream>>>(x, in_w, in_b, state_out, NROWS, STATE, DIMC);
    // bx = x1 @ B_w^T + B_b (shared by both directions via index reversal)
    gemm64<1><<<dim3(STATE/64, NROWS/64), dim3(256), 0, stream>>>(state_out, B_w, B_b, bxu, NROWS, STATE, STATE);
    scan_kernel<<<dim3(LSEQ/64, NBATCH, 2), dim3(128), 0, stream>>>(bxu, Amat, ylr, yrl);
    conv_combine<<<dim3(LSEQ, NBATCH), dim3(128), 0, stream>>>(ylr, yrl, conv_w, conv_b, bxu);
    fused_out<<<dim3(NROWS/32), dim3(256), 0, stream>>>(x, bxu, out_w, out_b, gate_w, gate_b,
                                                        norm_g, norm_b, yfinal);
    (void)in_sizes; (void)n_in; (void)out_size; (void)ws_size;
}

// Round 2
// 514.234 us; speedup vs baseline: 1.5782x; 1.5782x over previous
//
#include <hip/hip_runtime.h>
#include <hip/hip_bf16.h>

#define DIMC 256
#define STATE 128
#define RANK 64
#define NBATCH 16
#define LSEQ 4096
#define NROWS (NBATCH*LSEQ)   // 65536
#define LN_EPS 1e-5f

typedef __attribute__((ext_vector_type(8))) short frag8;   // 8 bf16 (4 VGPRs)
typedef __attribute__((ext_vector_type(4))) float f32x4;   // 4 fp32

// ---------------- At[j][i] = A[i][j] = sum_r V[i,r]*U[j,r], stored bf16 ----------------
__global__ __launch_bounds__(128) void a_kernel(const float* __restrict__ U, const float* __restrict__ V,
                                                __hip_bfloat16* __restrict__ At) {
    int i = blockIdx.x, j = threadIdx.x;
    float s = 0.f;
    #pragma unroll
    for (int r = 0; r < RANK; ++r) s += V[i*RANK + r] * U[j*RANK + r];
    At[j*STATE + i] = __float2bfloat16(s);   // h_new[j] = sum_i At[j][i]*h[i]
}

// ---------------- generic tiled fp32 GEMM: C = A @ Bw^T + bias ----------------
template<int AMODE>
__global__ __launch_bounds__(256) void gemm64(const float* __restrict__ Asrc, const float* __restrict__ Bw,
                                              const float* __restrict__ bias, float* __restrict__ C,
                                              int M, int N, int K) {
    __shared__ float As[16*68];
    __shared__ float Bs[16*68];
    const int t = threadIdx.x;
    const int n0blk = blockIdx.x * 64;
    const int r0 = blockIdx.y * 64;
    const int tx = t & 15, ty = t >> 4;
    float acc[4][4] = {};
    for (int k0 = 0; k0 < K; k0 += 16) {
        if (AMODE == 0) {
            const int b = r0 / LSEQ, lbase = r0 % LSEQ;
            const int ll = t & 63;
            #pragma unroll
            for (int i = 0; i < 4; ++i) {
                int cl = i*4 + (t>>6);
                As[cl*68 + ll] = Asrc[((size_t)b*DIMC + (k0+cl))*LSEQ + lbase + ll];
            }
        } else {
            #pragma unroll
            for (int i = 0; i < 4; ++i) {
                int ml = i*16 + (t>>4);
                int kl = t & 15;
                As[kl*68 + ml] = Asrc[(size_t)(r0+ml)*K + k0 + kl];
            }
        }
        #pragma unroll
        for (int i = 0; i < 4; ++i) {
            int nl = i*16 + (t>>4);
            int kl = t & 15;
            Bs[kl*68 + nl] = Bw[(size_t)(n0blk+nl)*K + k0 + kl];
        }
        __syncthreads();
        #pragma unroll
        for (int k = 0; k < 16; ++k) {
            float4 a4 = *(const float4*)(As + k*68 + ty*4);
            float4 b4 = *(const float4*)(Bs + k*68 + tx*4);
            float av[4] = {a4.x, a4.y, a4.z, a4.w};
            float bv[4] = {b4.x, b4.y, b4.z, b4.w};
            #pragma unroll
            for (int i = 0; i < 4; ++i)
                #pragma unroll
                for (int j = 0; j < 4; ++j)
                    acc[i][j] += av[i] * bv[j];
        }
        __syncthreads();
    }
    #pragma unroll
    for (int i = 0; i < 4; ++i) {
        size_t row = (size_t)r0 + ty*4 + i;
        #pragma unroll
        for (int j = 0; j < 4; ++j) {
            int col = n0blk + tx*4 + j;
            C[row*(size_t)N + col] = acc[i][j] + bias[col];
        }
    }
}

// ---------------- MFMA batched scan: 16 scans per wave, 1 wave per block ----------------
// Step: H^T(128x16) = At(128x128) * H^T + BX^T ; emit H^T each step.
#define HSTRIDE 144   // bf16 elements per column (128 + pad), 288 B: 16B-aligned b128 frags
__global__ __launch_bounds__(64, 1) void scan_mfma(const float* __restrict__ bx,
                                                   const __hip_bfloat16* __restrict__ At,
                                                   float* __restrict__ ylr, float* __restrict__ yrl) {
    __shared__ __hip_bfloat16 Hb[16 * HSTRIDE];
    const int l = threadIdx.x;      // 0..63
    const int c = l & 15;           // scan column this lane holds in B/D frags (also A-row field)
    const int q = l >> 4;           // 0..3

    const int S   = blockIdx.x * 16 + c;   // global scan id
    const int dir = S >> 10;
    const int b   = (S >> 6) & 15;
    const int blk = S & 63;
    const int lp0 = blk * 64;
    const int lorig0 = dir ? (LSEQ - 1 - lp0) : lp0;
    const int sgnstep = dir ? -STATE : STATE;

    const float* bxrow = bx + ((size_t)b*LSEQ + lorig0)*STATE;
    float* yrow = (dir ? yrl : ylr) + ((size_t)b*LSEQ + lp0)*STATE;

    // A^T fragments: tile m (output rows m*16..+15), chunk kc (k = kc*32..+31)
    frag8 afr[8][4];
    #pragma unroll
    for (int m = 0; m < 8; ++m)
        #pragma unroll
        for (int kc = 0; kc < 4; ++kc)
            afr[m][kc] = *(const frag8*)(At + (size_t)(m*16 + c)*STATE + kc*32 + q*8);

    // zero H
    for (int k = l; k < 16*HSTRIDE; k += 64) Hb[k] = __float2bfloat16(0.f);
    __syncthreads();

    // prefetch bx for t=0 (D-layout: 4 consecutive state rows per tile)
    f32x4 pf[8];
    #pragma unroll
    for (int m = 0; m < 8; ++m)
        pf[m] = *(const f32x4*)(bxrow + m*16 + q*4);

    for (int t = 0; t < 64; ++t) {
        // B fragments of current H
        frag8 bfr[4];
        #pragma unroll
        for (int kc = 0; kc < 4; ++kc)
            bfr[kc] = *(const frag8*)(&Hb[c*HSTRIDE + kc*32 + q*8]);

        f32x4 acc[8];
        #pragma unroll
        for (int m = 0; m < 8; ++m) {
            f32x4 a = {0.f, 0.f, 0.f, 0.f};
            #pragma unroll
            for (int kc = 0; kc < 4; ++kc)
                a = __builtin_amdgcn_mfma_f32_16x16x32_bf16(afr[m][kc], bfr[kc], a, 0, 0, 0);
            acc[m] = a;
        }

        // add bx (D-layout), then issue next-step prefetch (WAR after last use)
        #pragma unroll
        for (int m = 0; m < 8; ++m) acc[m] += pf[m];
        if (t < 63) {
            bxrow += sgnstep;
            #pragma unroll
            for (int m = 0; m < 8; ++m)
                pf[m] = *(const f32x4*)(bxrow + m*16 + q*4);
        }

        // store y (lanes q=0..3 of a column jointly cover full 64B lines)
        #pragma unroll
        for (int m = 0; m < 8; ++m)
            *(f32x4*)(yrow + m*16 + q*4) = acc[m];
        yrow += STATE;

        __syncthreads();   // all B-frag reads done before H update
        #pragma unroll
        for (int m = 0; m < 8; ++m) {
            union { __hip_bfloat16 h[4]; uint2 u; } pk;
            pk.h[0] = __float2bfloat16(acc[m][0]);
            pk.h[1] = __float2bfloat16(acc[m][1]);
            pk.h[2] = __float2bfloat16(acc[m][2]);
            pk.h[3] = __float2bfloat16(acc[m][3]);
            *(uint2*)(&Hb[c*HSTRIDE + m*16 + q*4]) = pk.u;
        }
        __syncthreads();   // H updated before next step's reads
    }
}

// ---------------- conv7 + direction combine: u = 0.5*(ulr + url) + conv_b ----------------
__global__ __launch_bounds__(128) void conv_combine(const float* __restrict__ ylr, const float* __restrict__ yrl,
                                                    const float* __restrict__ conv_w, const float* __restrict__ conv_b,
                                                    float* __restrict__ u) {
    const int s = threadIdx.x;
    const int l = blockIdx.x;
    const int b = blockIdx.y;
    float w[7];
    #pragma unroll
    for (int i = 0; i < 7; ++i) w[i] = conv_w[s*7 + i];
    const float* plr = ylr + (size_t)b*LSEQ*STATE;
    const float* prl = yrl + (size_t)b*LSEQ*STATE;
    float acc = plr[(size_t)l*STATE + s];
    #pragma unroll
    for (int i = 0; i < 7; ++i) {
        int qq = l - 3 + i;
        if (qq >= 0 && qq < LSEQ) acc += w[i] * plr[(size_t)qq*STATE + s];
    }
    const int lp = LSEQ - 1 - l;
    acc += prl[(size_t)lp*STATE + s];
    #pragma unroll
    for (int i = 0; i < 7; ++i) {
        int qq = lp - 3 + i;
        if (qq >= 0 && qq < LSEQ) acc += w[i] * prl[(size_t)qq*STATE + s];
    }
    u[((size_t)b*LSEQ + l)*STATE + s] = 0.5f*acc + conv_b[s];
}

// ---------------- fused: gate GEMM + out GEMM + sigmoid*o + residual + LN + transposed write ----
__global__ __launch_bounds__(256) void fused_out(const float* __restrict__ x, const float* __restrict__ u,
    const float* __restrict__ out_w, const float* __restrict__ out_b,
    const float* __restrict__ gate_w, const float* __restrict__ gate_b,
    const float* __restrict__ norm_g, const float* __restrict__ norm_b,
    float* __restrict__ y) {
    __shared__ float smem[32*257];
    __shared__ float mus[32], rstds[32];
    float* As = smem;
    float* Bs = smem + 576;
    const int t = threadIdx.x;
    const int r0 = blockIdx.x * 32;
    const int b = r0 / LSEQ, l0 = r0 % LSEQ;
    const int tx = t & 31, ty = t >> 5;
    const int m0 = ty*4, n0 = tx*8;
    float accg[4][8] = {};
    float acco[4][8] = {};
    for (int k0 = 0; k0 < DIMC; k0 += 16) {
        {
            int ll = t & 31;
            #pragma unroll
            for (int i = 0; i < 2; ++i) {
                int cl = i*8 + (t>>5);
                As[cl*36 + ll] = x[((size_t)b*DIMC + k0 + cl)*LSEQ + l0 + ll];
            }
        }
        #pragma unroll
        for (int i = 0; i < 16; ++i) {
            int nl = i*16 + (t>>4), kl = t & 15;
            Bs[kl*260 + nl] = gate_w[(size_t)nl*DIMC + k0 + kl];
        }
        __syncthreads();
        #pragma unroll
        for (int k = 0; k < 16; ++k) {
            float4 a4 = *(const float4*)(As + k*36 + m0);
            float4 bl = *(const float4*)(Bs + k*260 + n0);
            float4 bh = *(const float4*)(Bs + k*260 + n0 + 4);
            float av[4] = {a4.x,a4.y,a4.z,a4.w};
            float bv[8] = {bl.x,bl.y,bl.z,bl.w,bh.x,bh.y,bh.z,bh.w};
            #pragma unroll
            for (int i = 0; i < 4; ++i)
                #pragma unroll
                for (int j = 0; j < 8; ++j)
                    accg[i][j] += av[i]*bv[j];
        }
        __syncthreads();
    }
    for (int k0 = 0; k0 < STATE; k0 += 16) {
        #pragma unroll
        for (int i = 0; i < 2; ++i) {
            int ml = i*16 + (t>>4), kl = t & 15;
            As[kl*36 + ml] = u[(size_t)(r0+ml)*STATE + k0 + kl];
        }
        #pragma unroll
        for (int i = 0; i < 16; ++i) {
            int nl = i*16 + (t>>4), kl = t & 15;
            Bs[kl*260 + nl] = out_w[(size_t)nl*STATE + k0 + kl];
        }
        __syncthreads();
        #pragma unroll
        for (int k = 0; k < 16; ++k) {
            float4 a4 = *(const float4*)(As + k*36 + m0);
            float4 bl = *(const float4*)(Bs + k*260 + n0);
            float4 bh = *(const float4*)(Bs + k*260 + n0 + 4);
            float av[4] = {a4.x,a4.y,a4.z,a4.w};
            float bv[8] = {bl.x,bl.y,bl.z,bl.w,bh.x,bh.y,bh.z,bh.w};
            #pragma unroll
            for (int i = 0; i < 4; ++i)
                #pragma unroll
                for (int j = 0; j < 8; ++j)
                    acco[i][j] += av[i]*bv[j];
        }
        __syncthreads();
    }
    float* vbuf = smem;
    #pragma unroll
    for (int i = 0; i < 4; ++i) {
        int ll = l0 + m0 + i;
        #pragma unroll
        for (int j = 0; j < 8; ++j) {
            int cc = n0 + j;
            float xval = x[((size_t)b*DIMC + cc)*LSEQ + ll];
            float g = 1.f/(1.f + expf(-(accg[i][j] + gate_b[cc])));
            float o = acco[i][j] + out_b[cc];
            vbuf[(m0+i)*257 + cc] = g*o + xval;
        }
    }
    __syncthreads();
    {
        int rr = t >> 3, lane8 = t & 7;
        float s1 = 0.f, s2 = 0.f;
        #pragma unroll
        for (int k = 0; k < 32; ++k) {
            float v = vbuf[rr*257 + lane8 + 8*k];
            s1 += v; s2 += v*v;
        }
        s1 += __shfl_xor(s1, 1); s2 += __shfl_xor(s2, 1);
        s1 += __shfl_xor(s1, 2); s2 += __shfl_xor(s2, 2);
        s1 += __shfl_xor(s1, 4); s2 += __shfl_xor(s2, 4);
        if (lane8 == 0) {
            float mu = s1 * (1.f/256.f);
            float var = s2 * (1.f/256.f) - mu*mu;
            mus[rr] = mu;
            rstds[rr] = rsqrtf(var + LN_EPS);
        }
    }
    __syncthreads();
    {
        int cc = t;
        float g = norm_g[cc], be = norm_b[cc];
        float* outp = y + ((size_t)b*DIMC + cc)*LSEQ + l0;
        #pragma unroll
        for (int qq = 0; qq < 8; ++qq) {
            float4 v4;
            v4.x = (vbuf[(qq*4+0)*257 + cc] - mus[qq*4+0]) * rstds[qq*4+0] * g + be;
            v4.y = (vbuf[(qq*4+1)*257 + cc] - mus[qq*4+1]) * rstds[qq*4+1] * g + be;
            v4.z = (vbuf[(qq*4+2)*257 + cc] - mus[qq*4+2]) * rstds[qq*4+2] * g + be;
            v4.w = (vbuf[(qq*4+3)*257 + cc] - mus[qq*4+3]) * rstds[qq*4+3] * g + be;
            *(float4*)(outp + qq*4) = v4;
        }
    }
}

extern "C" void kernel_launch(void* const* d_in, const int* in_sizes, int n_in,
                              void* d_out, int out_size, void* d_ws, size_t ws_size,
                              hipStream_t stream) {
    const float* x      = (const float*)d_in[0];
    const float* in_w   = (const float*)d_in[1];
    const float* in_b   = (const float*)d_in[2];
    const float* U      = (const float*)d_in[3];
    const float* V      = (const float*)d_in[4];
    const float* B_w    = (const float*)d_in[5];
    const float* B_b    = (const float*)d_in[6];
    const float* out_w  = (const float*)d_in[7];
    const float* out_b  = (const float*)d_in[8];
    const float* gate_w = (const float*)d_in[9];
    const float* gate_b = (const float*)d_in[10];
    const float* norm_g = (const float*)d_in[11];
    const float* norm_b = (const float*)d_in[12];
    const float* conv_w = (const float*)d_in[13];
    const float* conv_b = (const float*)d_in[14];

    float* yfinal = (float*)d_out;                                 // [16][256][64][64]
    float* state_out = yfinal + (size_t)NBATCH*DIMC*LSEQ;          // [16][4096][128] == x1 (lr)

    float* ws  = (float*)d_ws;
    float* bxu = ws;                                               // NROWS*STATE: bx, later reused as u
    __hip_bfloat16* Atb16 = (__hip_bfloat16*)(ws + (size_t)NROWS*STATE);

    // scratch inside the y output region (overwritten by fused_out at the end):
    float* ylr = yfinal;                              // NROWS*STATE
    float* yrl = yfinal + (size_t)NROWS*STATE;        // NROWS*STATE

    a_kernel<<<dim3(STATE), dim3(STATE), 0, stream>>>(U, V, Atb16);
    gemm64<0><<<dim3(STATE/64, NROWS/64), dim3(256), 0, stream>>>(x, in_w, in_b, state_out, NROWS, STATE, DIMC);
    gemm64<1><<<dim3(STATE/64, NROWS/64), dim3(256), 0, stream>>>(state_out, B_w, B_b, bxu, NROWS, STATE, STATE);
    scan_mfma<<<dim3(128), dim3(64), 0, stream>>>(bxu, Atb16, ylr, yrl);
    conv_combine<<<dim3(LSEQ, NBATCH), dim3(128), 0, stream>>>(ylr, yrl, conv_w, conv_b, bxu);
    fused_out<<<dim3(NROWS/32), dim3(256), 0, stream>>>(x, bxu, out_w, out_b, gate_w, gate_b,
                                                        norm_g, norm_b, yfinal);
    (void)in_sizes; (void)n_in; (void)out_size; (void)ws_size;
}

// Round 3
// 346.987 us; speedup vs baseline: 2.3389x; 1.4820x over previous
//
#include <hip/hip_runtime.h>
#include <hip/hip_bf16.h>

#define DIMC 256
#define STATE 128
#define RANK 64
#define NBATCH 16
#define LSEQ 4096
#define NROWS (NBATCH*LSEQ)   // 65536
#define LN_EPS 1e-5f

typedef __attribute__((ext_vector_type(8))) short frag8;   // 8 bf16 (4 VGPRs)
typedef __attribute__((ext_vector_type(4))) float f32x4;   // 4 fp32

union AFrag { __hip_bfloat16 h[8]; frag8 f; };

// ---------------- At[j][i] = A[i][j] = sum_r V[i,r]*U[j,r], stored bf16 ----------------
__global__ __launch_bounds__(128) void a_kernel(const float* __restrict__ U, const float* __restrict__ V,
                                                __hip_bfloat16* __restrict__ At) {
    int i = blockIdx.x, j = threadIdx.x;
    float s = 0.f;
    #pragma unroll
    for (int r = 0; r < RANK; ++r) s += V[i*RANK + r] * U[j*RANK + r];
    At[j*STATE + i] = __float2bfloat16(s);   // h_new[j] = sum_i At[j][i]*h[i]
}

// ---------------- weights fp32 -> bf16 (row-major preserved) ----------------
__global__ __launch_bounds__(256) void prep_weights(const float* __restrict__ in_w, const float* __restrict__ B_w,
                                                    const float* __restrict__ gate_w, const float* __restrict__ out_w,
                                                    __hip_bfloat16* __restrict__ in_wb, __hip_bfloat16* __restrict__ B_wb,
                                                    __hip_bfloat16* __restrict__ gate_wb, __hip_bfloat16* __restrict__ out_wb) {
    int idx = blockIdx.x*256 + threadIdx.x;
    int which = blockIdx.y;
    if (which == 0) { if (idx < STATE*DIMC)  in_wb[idx]   = __float2bfloat16(in_w[idx]); }
    else if (which == 1) { if (idx < STATE*STATE) B_wb[idx] = __float2bfloat16(B_w[idx]); }
    else if (which == 2) { if (idx < DIMC*DIMC)  gate_wb[idx] = __float2bfloat16(gate_w[idx]); }
    else { if (idx < DIMC*STATE) out_wb[idx] = __float2bfloat16(out_w[idx]); }
}

// ---------------- MFMA GEMM: C[l][s] = sum_c x[b][c][l]*W[s][c] + bias, N=128, K=256 ----------------
// block = 64 l x 128 s, 4 waves (16 l each); A-frags gathered from channel-major x, converted to bf16.
__global__ __launch_bounds__(256) void gemm_in_mfma(const float* __restrict__ x, const __hip_bfloat16* __restrict__ Wb,
                                                    const float* __restrict__ bias, float* __restrict__ C) {
    const int t = threadIdx.x;
    const int lane = t & 63;
    const int c = lane & 15, q = lane >> 4;
    const int wm = t >> 6;                 // wave id 0..3
    const int r0 = blockIdx.x * 64;
    const int b = r0 >> 12, l0 = r0 & 4095;
    const float* xp = x + (size_t)b*DIMC*LSEQ + (l0 + wm*16 + c);

    f32x4 acc[8] = {};
    for (int k0 = 0; k0 < DIMC; k0 += 32) {
        AFrag af;
        #pragma unroll
        for (int j = 0; j < 8; ++j)
            af.h[j] = __float2bfloat16(xp[(size_t)(k0 + q*8 + j)*LSEQ]);
        #pragma unroll
        for (int nt = 0; nt < 8; ++nt) {
            frag8 bf = *(const frag8*)(Wb + (size_t)(nt*16 + c)*DIMC + k0 + q*8);
            acc[nt] = __builtin_amdgcn_mfma_f32_16x16x32_bf16(af.f, bf, acc[nt], 0, 0, 0);
        }
    }
    const int orow = r0 + wm*16 + q*4;
    #pragma unroll
    for (int nt = 0; nt < 8; ++nt) {
        float bb = bias[nt*16 + c];
        #pragma unroll
        for (int r = 0; r < 4; ++r)
            C[(size_t)(orow + r)*STATE + nt*16 + c] = acc[nt][r] + bb;
    }
}

// ---------------- MFMA GEMM: C[l][s'] = sum_s X1[l][s]*W[s'][s] + bias, N=128, K=128 ----------------
__global__ __launch_bounds__(256) void gemm_B_mfma(const float* __restrict__ X1, const __hip_bfloat16* __restrict__ Wb,
                                                   const float* __restrict__ bias, float* __restrict__ C) {
    const int t = threadIdx.x;
    const int lane = t & 63;
    const int c = lane & 15, q = lane >> 4;
    const int wm = t >> 6;
    const int r0 = blockIdx.x * 64;
    const int arow = r0 + wm*16 + c;

    f32x4 acc[8] = {};
    for (int k0 = 0; k0 < STATE; k0 += 32) {
        AFrag af;
        float4 v0 = *(const float4*)(X1 + (size_t)arow*STATE + k0 + q*8);
        float4 v1 = *(const float4*)(X1 + (size_t)arow*STATE + k0 + q*8 + 4);
        af.h[0] = __float2bfloat16(v0.x); af.h[1] = __float2bfloat16(v0.y);
        af.h[2] = __float2bfloat16(v0.z); af.h[3] = __float2bfloat16(v0.w);
        af.h[4] = __float2bfloat16(v1.x); af.h[5] = __float2bfloat16(v1.y);
        af.h[6] = __float2bfloat16(v1.z); af.h[7] = __float2bfloat16(v1.w);
        #pragma unroll
        for (int nt = 0; nt < 8; ++nt) {
            frag8 bf = *(const frag8*)(Wb + (size_t)(nt*16 + c)*STATE + k0 + q*8);
            acc[nt] = __builtin_amdgcn_mfma_f32_16x16x32_bf16(af.f, bf, acc[nt], 0, 0, 0);
        }
    }
    const int orow = r0 + wm*16 + q*4;
    #pragma unroll
    for (int nt = 0; nt < 8; ++nt) {
        float bb = bias[nt*16 + c];
        #pragma unroll
        for (int r = 0; r < 4; ++r)
            C[(size_t)(orow + r)*STATE + nt*16 + c] = acc[nt][r] + bb;
    }
}

// ---------------- MFMA batched scan: 16 scans per wave, 1 wave per block ----------------
#define HSTRIDE 144
__global__ __launch_bounds__(64, 1) void scan_mfma(const float* __restrict__ bx,
                                                   const __hip_bfloat16* __restrict__ At,
                                                   float* __restrict__ ylr, float* __restrict__ yrl) {
    __shared__ __hip_bfloat16 Hb[16 * HSTRIDE];
    const int l = threadIdx.x;
    const int c = l & 15;
    const int q = l >> 4;

    const int S   = blockIdx.x * 16 + c;
    const int dir = S >> 10;
    const int b   = (S >> 6) & 15;
    const int blk = S & 63;
    const int lp0 = blk * 64;
    const int lorig0 = dir ? (LSEQ - 1 - lp0) : lp0;
    const int sgnstep = dir ? -STATE : STATE;

    const float* bxrow = bx + ((size_t)b*LSEQ + lorig0)*STATE;
    float* yrow = (dir ? yrl : ylr) + ((size_t)b*LSEQ + lp0)*STATE;

    frag8 afr[8][4];
    #pragma unroll
    for (int m = 0; m < 8; ++m)
        #pragma unroll
        for (int kc = 0; kc < 4; ++kc)
            afr[m][kc] = *(const frag8*)(At + (size_t)(m*16 + c)*STATE + kc*32 + q*8);

    for (int k = l; k < 16*HSTRIDE; k += 64) Hb[k] = __float2bfloat16(0.f);
    __syncthreads();

    f32x4 pf[8];
    #pragma unroll
    for (int m = 0; m < 8; ++m)
        pf[m] = *(const f32x4*)(bxrow + m*16 + q*4);

    for (int t = 0; t < 64; ++t) {
        frag8 bfr[4];
        #pragma unroll
        for (int kc = 0; kc < 4; ++kc)
            bfr[kc] = *(const frag8*)(&Hb[c*HSTRIDE + kc*32 + q*8]);

        f32x4 acc[8];
        #pragma unroll
        for (int m = 0; m < 8; ++m) {
            f32x4 a = {0.f, 0.f, 0.f, 0.f};
            #pragma unroll
            for (int kc = 0; kc < 4; ++kc)
                a = __builtin_amdgcn_mfma_f32_16x16x32_bf16(afr[m][kc], bfr[kc], a, 0, 0, 0);
            acc[m] = a;
        }

        #pragma unroll
        for (int m = 0; m < 8; ++m) acc[m] += pf[m];
        if (t < 63) {
            bxrow += sgnstep;
            #pragma unroll
            for (int m = 0; m < 8; ++m)
                pf[m] = *(const f32x4*)(bxrow + m*16 + q*4);
        }

        #pragma unroll
        for (int m = 0; m < 8; ++m)
            *(f32x4*)(yrow + m*16 + q*4) = acc[m];
        yrow += STATE;

        __syncthreads();
        #pragma unroll
        for (int m = 0; m < 8; ++m) {
            union { __hip_bfloat16 h[4]; uint2 u; } pk;
            pk.h[0] = __float2bfloat16(acc[m][0]);
            pk.h[1] = __float2bfloat16(acc[m][1]);
            pk.h[2] = __float2bfloat16(acc[m][2]);
            pk.h[3] = __float2bfloat16(acc[m][3]);
            *(uint2*)(&Hb[c*HSTRIDE + m*16 + q*4]) = pk.u;
        }
        __syncthreads();
    }
}

// ---------------- conv7 + direction combine: u = 0.5*(ulr + url) + conv_b ----------------
__global__ __launch_bounds__(128) void conv_combine(const float* __restrict__ ylr, const float* __restrict__ yrl,
                                                    const float* __restrict__ conv_w, const float* __restrict__ conv_b,
                                                    float* __restrict__ u) {
    const int s = threadIdx.x;
    const int l = blockIdx.x;
    const int b = blockIdx.y;
    float w[7];
    #pragma unroll
    for (int i = 0; i < 7; ++i) w[i] = conv_w[s*7 + i];
    const float* plr = ylr + (size_t)b*LSEQ*STATE;
    const float* prl = yrl + (size_t)b*LSEQ*STATE;
    float acc = plr[(size_t)l*STATE + s];
    #pragma unroll
    for (int i = 0; i < 7; ++i) {
        int qq = l - 3 + i;
        if (qq >= 0 && qq < LSEQ) acc += w[i] * plr[(size_t)qq*STATE + s];
    }
    const int lp = LSEQ - 1 - l;
    acc += prl[(size_t)lp*STATE + s];
    #pragma unroll
    for (int i = 0; i < 7; ++i) {
        int qq = lp - 3 + i;
        if (qq >= 0 && qq < LSEQ) acc += w[i] * prl[(size_t)qq*STATE + s];
    }
    u[((size_t)b*LSEQ + l)*STATE + s] = 0.5f*acc + conv_b[s];
}

// ---------------- fused MFMA: gate GEMM + out GEMM + sigmoid*o + residual + LN + transposed write ----
// block = 32 l x 256 c; 4 waves in 2(M) x 2(N): each wave 16 l x 128 c.
__global__ __launch_bounds__(256) void fused_out(const float* __restrict__ x, const float* __restrict__ u,
    const __hip_bfloat16* __restrict__ out_wb, const float* __restrict__ out_b,
    const __hip_bfloat16* __restrict__ gate_wb, const float* __restrict__ gate_b,
    const float* __restrict__ norm_g, const float* __restrict__ norm_b,
    float* __restrict__ y) {
    __shared__ float vbuf[32*260];
    __shared__ float mus[32], rstds[32];
    const int t = threadIdx.x;
    const int lane = t & 63, c = lane & 15, q = lane >> 4;
    const int w = t >> 6, wm = w >> 1, wc = w & 1;
    const int r0 = blockIdx.x * 32;
    const int b = r0 >> 12, l0 = r0 & 4095;

    // gate GEMM (K = 256 channels of x)
    f32x4 accg[8] = {};
    {
        const float* xp = x + (size_t)b*DIMC*LSEQ + (l0 + wm*16 + c);
        for (int k0 = 0; k0 < DIMC; k0 += 32) {
            AFrag af;
            #pragma unroll
            for (int j = 0; j < 8; ++j)
                af.h[j] = __float2bfloat16(xp[(size_t)(k0 + q*8 + j)*LSEQ]);
            #pragma unroll
            for (int nt = 0; nt < 8; ++nt) {
                frag8 bf = *(const frag8*)(gate_wb + (size_t)(wc*128 + nt*16 + c)*DIMC + k0 + q*8);
                accg[nt] = __builtin_amdgcn_mfma_f32_16x16x32_bf16(af.f, bf, accg[nt], 0, 0, 0);
            }
        }
    }
    // out GEMM (K = 128 states of u)
    f32x4 acco[8] = {};
    {
        const int arow = r0 + wm*16 + c;
        for (int k0 = 0; k0 < STATE; k0 += 32) {
            AFrag af;
            float4 v0 = *(const float4*)(u + (size_t)arow*STATE + k0 + q*8);
            float4 v1 = *(const float4*)(u + (size_t)arow*STATE + k0 + q*8 + 4);
            af.h[0] = __float2bfloat16(v0.x); af.h[1] = __float2bfloat16(v0.y);
            af.h[2] = __float2bfloat16(v0.z); af.h[3] = __float2bfloat16(v0.w);
            af.h[4] = __float2bfloat16(v1.x); af.h[5] = __float2bfloat16(v1.y);
            af.h[6] = __float2bfloat16(v1.z); af.h[7] = __float2bfloat16(v1.w);
            #pragma unroll
            for (int nt = 0; nt < 8; ++nt) {
                frag8 bf = *(const frag8*)(out_wb + (size_t)(wc*128 + nt*16 + c)*STATE + k0 + q*8);
                acco[nt] = __builtin_amdgcn_mfma_f32_16x16x32_bf16(af.f, bf, acco[nt], 0, 0, 0);
            }
        }
    }
    // epilogue: v = sigmoid(gate)*o + residual  (D-layout: row = q*4+r, col = lane&15)
    #pragma unroll
    for (int nt = 0; nt < 8; ++nt) {
        int col = wc*128 + nt*16 + c;
        float gb = gate_b[col], ob = out_b[col];
        const float* xr = x + ((size_t)b*DIMC + col)*LSEQ + l0 + wm*16 + q*4;
        #pragma unroll
        for (int r = 0; r < 4; ++r) {
            float g = 1.f/(1.f + expf(-(accg[nt][r] + gb)));
            float o = acco[nt][r] + ob;
            vbuf[(wm*16 + q*4 + r)*260 + col] = g*o + xr[r];
        }
    }
    __syncthreads();
    // LayerNorm stats: 8 threads per row
    {
        int rr = t >> 3, lane8 = t & 7;
        float s1 = 0.f, s2 = 0.f;
        #pragma unroll
        for (int k = 0; k < 32; ++k) {
            float v = vbuf[rr*260 + lane8 + 8*k];
            s1 += v; s2 += v*v;
        }
        s1 += __shfl_xor(s1, 1); s2 += __shfl_xor(s2, 1);
        s1 += __shfl_xor(s1, 2); s2 += __shfl_xor(s2, 2);
        s1 += __shfl_xor(s1, 4); s2 += __shfl_xor(s2, 4);
        if (lane8 == 0) {
            float mu = s1 * (1.f/256.f);
            float var = s2 * (1.f/256.f) - mu*mu;
            mus[rr] = mu;
            rstds[rr] = rsqrtf(var + LN_EPS);
        }
    }
    __syncthreads();
    // transposed write: thread t = channel c, 32 consecutive l as 8x float4
    {
        int cc = t;
        float g = norm_g[cc], be = norm_b[cc];
        float* outp = y + ((size_t)b*DIMC + cc)*LSEQ + l0;
        #pragma unroll
        for (int qq = 0; qq < 8; ++qq) {
            float4 v4;
            v4.x = (vbuf[(qq*4+0)*260 + cc] - mus[qq*4+0]) * rstds[qq*4+0] * g + be;
            v4.y = (vbuf[(qq*4+1)*260 + cc] - mus[qq*4+1]) * rstds[qq*4+1] * g + be;
            v4.z = (vbuf[(qq*4+2)*260 + cc] - mus[qq*4+2]) * rstds[qq*4+2] * g + be;
            v4.w = (vbuf[(qq*4+3)*260 + cc] - mus[qq*4+3]) * rstds[qq*4+3] * g + be;
            *(float4*)(outp + qq*4) = v4;
        }
    }
}

extern "C" void kernel_launch(void* const* d_in, const int* in_sizes, int n_in,
                              void* d_out, int out_size, void* d_ws, size_t ws_size,
                              hipStream_t stream) {
    const float* x      = (const float*)d_in[0];
    const float* in_w   = (const float*)d_in[1];
    const float* in_b   = (const float*)d_in[2];
    const float* U      = (const float*)d_in[3];
    const float* V      = (const float*)d_in[4];
    const float* B_w    = (const float*)d_in[5];
    const float* B_b    = (const float*)d_in[6];
    const float* out_w  = (const float*)d_in[7];
    const float* out_b  = (const float*)d_in[8];
    const float* gate_w = (const float*)d_in[9];
    const float* gate_b = (const float*)d_in[10];
    const float* norm_g = (const float*)d_in[11];
    const float* norm_b = (const float*)d_in[12];
    const float* conv_w = (const float*)d_in[13];
    const float* conv_b = (const float*)d_in[14];

    float* yfinal = (float*)d_out;                                 // [16][256][64][64]
    float* state_out = yfinal + (size_t)NBATCH*DIMC*LSEQ;          // [16][4096][128] == x1 (lr)

    float* ws  = (float*)d_ws;
    float* bxu = ws;                                               // NROWS*STATE fp32: bx, later u
    __hip_bfloat16* Atb16  = (__hip_bfloat16*)(ws + (size_t)NROWS*STATE);
    __hip_bfloat16* in_wb  = Atb16 + STATE*STATE;
    __hip_bfloat16* B_wb   = in_wb + STATE*DIMC;
    __hip_bfloat16* gate_wb= B_wb + STATE*STATE;
    __hip_bfloat16* out_wb = gate_wb + DIMC*DIMC;

    // scratch inside the y output region (overwritten by fused_out at the end):
    float* ylr = yfinal;                              // NROWS*STATE
    float* yrl = yfinal + (size_t)NROWS*STATE;        // NROWS*STATE

    a_kernel<<<dim3(STATE), dim3(STATE), 0, stream>>>(U, V, Atb16);
    prep_weights<<<dim3(256, 4), dim3(256), 0, stream>>>(in_w, B_w, gate_w, out_w,
                                                         in_wb, B_wb, gate_wb, out_wb);
    gemm_in_mfma<<<dim3(NROWS/64), dim3(256), 0, stream>>>(x, in_wb, in_b, state_out);
    gemm_B_mfma<<<dim3(NROWS/64), dim3(256), 0, stream>>>(state_out, B_wb, B_b, bxu);
    scan_mfma<<<dim3(128), dim3(64), 0, stream>>>(bxu, Atb16, ylr, yrl);
    conv_combine<<<dim3(LSEQ, NBATCH), dim3(128), 0, stream>>>(ylr, yrl, conv_w, conv_b, bxu);
    fused_out<<<dim3(NROWS/32), dim3(256), 0, stream>>>(x, bxu, out_wb, out_b, gate_wb, gate_b,
                                                        norm_g, norm_b, yfinal);
    (void)in_sizes; (void)n_in; (void)out_size; (void)ws_size;
}

// Round 4
// 293.864 us; speedup vs baseline: 2.7617x; 1.1808x over previous
//
#include <hip/hip_runtime.h>
#include <hip/hip_bf16.h>

#define DIMC 256
#define STATE 128
#define RANK 64
#define NBATCH 16
#define LSEQ 4096
#define NROWS (NBATCH*LSEQ)   // 65536
#define LN_EPS 1e-5f
#define XSTR 264              // LDS row stride (bf16 elems) for staged x tiles

typedef __attribute__((ext_vector_type(8))) short frag8;   // 8 bf16 (4 VGPRs)
typedef __attribute__((ext_vector_type(4))) float f32x4;   // 4 fp32

union AFrag { __hip_bfloat16 h[8]; frag8 f; };
union Pack4 { __hip_bfloat16 h[4]; uint2 u; };
union Pack8 { __hip_bfloat16 h[8]; uint4 u; };

// ---------------- At[j][i] = A[i][j] = sum_r V[i,r]*U[j,r], stored bf16 ----------------
__global__ __launch_bounds__(128) void a_kernel(const float* __restrict__ U, const float* __restrict__ V,
                                                __hip_bfloat16* __restrict__ At) {
    int i = blockIdx.x, j = threadIdx.x;
    float s = 0.f;
    #pragma unroll
    for (int r = 0; r < RANK; ++r) s += V[i*RANK + r] * U[j*RANK + r];
    At[j*STATE + i] = __float2bfloat16(s);
}

// ---------------- weights fp32 -> bf16 ----------------
__global__ __launch_bounds__(256) void prep_weights(const float* __restrict__ in_w, const float* __restrict__ B_w,
                                                    const float* __restrict__ gate_w, const float* __restrict__ out_w,
                                                    __hip_bfloat16* __restrict__ in_wb, __hip_bfloat16* __restrict__ B_wb,
                                                    __hip_bfloat16* __restrict__ gate_wb, __hip_bfloat16* __restrict__ out_wb) {
    int idx = blockIdx.x*256 + threadIdx.x;
    int which = blockIdx.y;
    if (which == 0) { if (idx < STATE*DIMC)  in_wb[idx]   = __float2bfloat16(in_w[idx]); }
    else if (which == 1) { if (idx < STATE*STATE) B_wb[idx] = __float2bfloat16(B_w[idx]); }
    else if (which == 2) { if (idx < DIMC*DIMC)  gate_wb[idx] = __float2bfloat16(gate_w[idx]); }
    else { if (idx < DIMC*STATE) out_wb[idx] = __float2bfloat16(out_w[idx]); }
}

// ---- stage x[b][0..255][l0..l0+LROWS) into LDS bf16 [l][cin^((l&3)<<3)], stride XSTR ----
// coalesced: 4 lanes x float4 = 64B per channel line; swizzle makes ds_write 2-way (free)
template<int LROWS>
__device__ inline void stage_x_tile(const float* __restrict__ xb, int l0,
                                    __hip_bfloat16* __restrict__ xs, int t) {
    constexpr int NP = LROWS/4;
    #pragma unroll
    for (int p = 0; p < NP; ++p) {
        int cin = (t>>2) + (p&3)*64;
        int lq  = (t&3) + (p>>2)*4;
        float4 v = *(const float4*)(xb + (size_t)cin*LSEQ + l0 + lq*4);
        int lb = lq*4;
        xs[(size_t)(lb+0)*XSTR + (cin ^ 0 )] = __float2bfloat16(v.x);
        xs[(size_t)(lb+1)*XSTR + (cin ^ 8 )] = __float2bfloat16(v.y);
        xs[(size_t)(lb+2)*XSTR + (cin ^ 16)] = __float2bfloat16(v.z);
        xs[(size_t)(lb+3)*XSTR + (cin ^ 24)] = __float2bfloat16(v.w);
    }
}
__device__ inline frag8 ld_xfrag(const __hip_bfloat16* __restrict__ xs, int row, int k) {
    return *(const frag8*)(xs + (size_t)row*XSTR + (k ^ ((row&3)<<3)));
}

// ---------------- MFMA GEMM: x1[l][s] = sum_c x[b][c][l]*W[s][c] + bias ----------------
// block = 64 l x 128 s, 4 waves (16 l each), x-tile staged through LDS
__global__ __launch_bounds__(256) void gemm_in_mfma(const float* __restrict__ x, const __hip_bfloat16* __restrict__ Wb,
                                                    const float* __restrict__ bias, float* __restrict__ C) {
    __shared__ __hip_bfloat16 xs[64*XSTR];
    const int t = threadIdx.x;
    const int lane = t & 63;
    const int c = lane & 15, q = lane >> 4;
    const int wm = t >> 6;
    const int r0 = blockIdx.x * 64;
    const int b = r0 >> 12, l0 = r0 & 4095;

    stage_x_tile<64>(x + (size_t)b*DIMC*LSEQ, l0, xs, t);
    __syncthreads();

    f32x4 acc[8] = {};
    for (int k0 = 0; k0 < DIMC; k0 += 32) {
        frag8 af = ld_xfrag(xs, wm*16 + c, k0 + q*8);
        #pragma unroll
        for (int nt = 0; nt < 8; ++nt) {
            frag8 bf = *(const frag8*)(Wb + (size_t)(nt*16 + c)*DIMC + k0 + q*8);
            acc[nt] = __builtin_amdgcn_mfma_f32_16x16x32_bf16(af, bf, acc[nt], 0, 0, 0);
        }
    }
    const int orow = r0 + wm*16 + q*4;
    #pragma unroll
    for (int nt = 0; nt < 8; ++nt) {
        float bb = bias[nt*16 + c];
        #pragma unroll
        for (int r = 0; r < 4; ++r)
            C[(size_t)(orow + r)*STATE + nt*16 + c] = acc[nt][r] + bb;
    }
}

// ---------------- MFMA GEMM: bx[l][s'] = sum_s X1[l][s]*W[s'][s] + bias ----------------
__global__ __launch_bounds__(256) void gemm_B_mfma(const float* __restrict__ X1, const __hip_bfloat16* __restrict__ Wb,
                                                   const float* __restrict__ bias, float* __restrict__ C) {
    const int t = threadIdx.x;
    const int lane = t & 63;
    const int c = lane & 15, q = lane >> 4;
    const int wm = t >> 6;
    const int r0 = blockIdx.x * 64;
    const int arow = r0 + wm*16 + c;

    f32x4 acc[8] = {};
    for (int k0 = 0; k0 < STATE; k0 += 32) {
        AFrag af;
        float4 v0 = *(const float4*)(X1 + (size_t)arow*STATE + k0 + q*8);
        float4 v1 = *(const float4*)(X1 + (size_t)arow*STATE + k0 + q*8 + 4);
        af.h[0] = __float2bfloat16(v0.x); af.h[1] = __float2bfloat16(v0.y);
        af.h[2] = __float2bfloat16(v0.z); af.h[3] = __float2bfloat16(v0.w);
        af.h[4] = __float2bfloat16(v1.x); af.h[5] = __float2bfloat16(v1.y);
        af.h[6] = __float2bfloat16(v1.z); af.h[7] = __float2bfloat16(v1.w);
        #pragma unroll
        for (int nt = 0; nt < 8; ++nt) {
            frag8 bf = *(const frag8*)(Wb + (size_t)(nt*16 + c)*STATE + k0 + q*8);
            acc[nt] = __builtin_amdgcn_mfma_f32_16x16x32_bf16(af.f, bf, acc[nt], 0, 0, 0);
        }
    }
    const int orow = r0 + wm*16 + q*4;
    #pragma unroll
    for (int nt = 0; nt < 8; ++nt) {
        float bb = bias[nt*16 + c];
        #pragma unroll
        for (int r = 0; r < 4; ++r)
            C[(size_t)(orow + r)*STATE + nt*16 + c] = acc[nt][r] + bb;
    }
}

// ---------------- MFMA batched scan: 16 scans per wave; y outputs bf16 ----------------
#define HSTRIDE 144
__global__ __launch_bounds__(64, 1) void scan_mfma(const float* __restrict__ bx,
                                                   const __hip_bfloat16* __restrict__ At,
                                                   __hip_bfloat16* __restrict__ ylr,
                                                   __hip_bfloat16* __restrict__ yrl) {
    __shared__ __hip_bfloat16 Hb[16 * HSTRIDE];
    const int l = threadIdx.x;
    const int c = l & 15;
    const int q = l >> 4;

    const int S   = blockIdx.x * 16 + c;
    const int dir = S >> 10;
    const int b   = (S >> 6) & 15;
    const int blk = S & 63;
    const int lp0 = blk * 64;
    const int lorig0 = dir ? (LSEQ - 1 - lp0) : lp0;
    const int sgnstep = dir ? -STATE : STATE;

    const float* bxrow = bx + ((size_t)b*LSEQ + lorig0)*STATE;
    __hip_bfloat16* yrow = (dir ? yrl : ylr) + ((size_t)b*LSEQ + lp0)*STATE;

    frag8 afr[8][4];
    #pragma unroll
    for (int m = 0; m < 8; ++m)
        #pragma unroll
        for (int kc = 0; kc < 4; ++kc)
            afr[m][kc] = *(const frag8*)(At + (size_t)(m*16 + c)*STATE + kc*32 + q*8);

    for (int k = l; k < 16*HSTRIDE; k += 64) Hb[k] = __float2bfloat16(0.f);
    __syncthreads();

    f32x4 pf[8];
    #pragma unroll
    for (int m = 0; m < 8; ++m)
        pf[m] = *(const f32x4*)(bxrow + m*16 + q*4);

    for (int t = 0; t < 64; ++t) {
        frag8 bfr[4];
        #pragma unroll
        for (int kc = 0; kc < 4; ++kc)
            bfr[kc] = *(const frag8*)(&Hb[c*HSTRIDE + kc*32 + q*8]);

        f32x4 acc[8];
        #pragma unroll
        for (int m = 0; m < 8; ++m) {
            f32x4 a = {0.f, 0.f, 0.f, 0.f};
            #pragma unroll
            for (int kc = 0; kc < 4; ++kc)
                a = __builtin_amdgcn_mfma_f32_16x16x32_bf16(afr[m][kc], bfr[kc], a, 0, 0, 0);
            acc[m] = a;
        }

        #pragma unroll
        for (int m = 0; m < 8; ++m) acc[m] += pf[m];
        if (t < 63) {
            bxrow += sgnstep;
            #pragma unroll
            for (int m = 0; m < 8; ++m)
                pf[m] = *(const f32x4*)(bxrow + m*16 + q*4);
        }

        // pack once; reuse for global y store and LDS H update
        Pack4 pk[8];
        #pragma unroll
        for (int m = 0; m < 8; ++m) {
            pk[m].h[0] = __float2bfloat16(acc[m][0]);
            pk[m].h[1] = __float2bfloat16(acc[m][1]);
            pk[m].h[2] = __float2bfloat16(acc[m][2]);
            pk[m].h[3] = __float2bfloat16(acc[m][3]);
        }
        #pragma unroll
        for (int m = 0; m < 8; ++m)
            *(uint2*)(yrow + m*16 + q*4) = pk[m].u;
        yrow += STATE;

        __syncthreads();
        #pragma unroll
        for (int m = 0; m < 8; ++m)
            *(uint2*)(&Hb[c*HSTRIDE + m*16 + q*4]) = pk[m].u;
        __syncthreads();
    }
}

// ---------------- conv7 + combine: u = 0.5*(conv(ylr)+rev(conv(yrl))) + conv_b, bf16 io ----------------
// block: 8 l x 128 s; thread handles 8 channels via uint4 (8 bf16) loads
__global__ __launch_bounds__(128) void conv_combine(const __hip_bfloat16* __restrict__ ylr,
                                                    const __hip_bfloat16* __restrict__ yrl,
                                                    const float* __restrict__ conv_w, const float* __restrict__ conv_b,
                                                    __hip_bfloat16* __restrict__ u) {
    const int t = threadIdx.x;
    const int s8 = (t & 15) * 8;
    const int l = blockIdx.x * 8 + (t >> 4);
    const int b = blockIdx.y;

    float wv[8][7];
    #pragma unroll
    for (int j = 0; j < 8; ++j)
        #pragma unroll
        for (int i = 0; i < 7; ++i) wv[j][i] = conv_w[(s8+j)*7 + i];

    const __hip_bfloat16* plr = ylr + (size_t)b*LSEQ*STATE;
    const __hip_bfloat16* prl = yrl + (size_t)b*LSEQ*STATE;

    float acc[8];
    {   // lr center
        Pack8 v; v.u = *(const uint4*)(plr + (size_t)l*STATE + s8);
        #pragma unroll
        for (int j = 0; j < 8; ++j) acc[j] = __bfloat162float(v.h[j]);
    }
    #pragma unroll
    for (int i = 0; i < 7; ++i) {
        int qq = l - 3 + i;
        if (qq >= 0 && qq < LSEQ) {
            Pack8 v; v.u = *(const uint4*)(plr + (size_t)qq*STATE + s8);
            #pragma unroll
            for (int j = 0; j < 8; ++j) acc[j] += wv[j][i] * __bfloat162float(v.h[j]);
        }
    }
    const int lp = LSEQ - 1 - l;
    {   // rl center
        Pack8 v; v.u = *(const uint4*)(prl + (size_t)lp*STATE + s8);
        #pragma unroll
        for (int j = 0; j < 8; ++j) acc[j] += __bfloat162float(v.h[j]);
    }
    #pragma unroll
    for (int i = 0; i < 7; ++i) {
        int qq = lp - 3 + i;
        if (qq >= 0 && qq < LSEQ) {
            Pack8 v; v.u = *(const uint4*)(prl + (size_t)qq*STATE + s8);
            #pragma unroll
            for (int j = 0; j < 8; ++j) acc[j] += wv[j][i] * __bfloat162float(v.h[j]);
        }
    }
    Pack8 o;
    #pragma unroll
    for (int j = 0; j < 8; ++j) o.h[j] = __float2bfloat16(0.5f*acc[j] + conv_b[s8+j]);
    *(uint4*)(u + ((size_t)b*LSEQ + l)*STATE + s8) = o.u;
}

// ---------------- fused MFMA: gate GEMM + out GEMM + sigmoid*o + residual + LN + transposed write ----
// block = 32 l x 256 c; 4 waves in 2(M) x 2(N). x-tile LDS-staged; u is bf16.
__global__ __launch_bounds__(256) void fused_out(const float* __restrict__ x, const __hip_bfloat16* __restrict__ ub,
    const __hip_bfloat16* __restrict__ out_wb, const float* __restrict__ out_b,
    const __hip_bfloat16* __restrict__ gate_wb, const float* __restrict__ gate_b,
    const float* __restrict__ norm_g, const float* __restrict__ norm_b,
    float* __restrict__ y) {
    __shared__ float vbuf[32*260];                 // 33280 B; aliased as xs during GEMMs
    __shared__ float mus[32], rstds[32];
    __hip_bfloat16* xs = (__hip_bfloat16*)vbuf;    // 32 x XSTR bf16 = 16896 B
    const int t = threadIdx.x;
    const int lane = t & 63, c = lane & 15, q = lane >> 4;
    const int w = t >> 6, wm = w >> 1, wc = w & 1;
    const int r0 = blockIdx.x * 32;
    const int b = r0 >> 12, l0 = r0 & 4095;

    stage_x_tile<32>(x + (size_t)b*DIMC*LSEQ, l0, xs, t);
    __syncthreads();

    // gate GEMM (K = 256 channels of x, A from LDS)
    f32x4 accg[8] = {};
    for (int k0 = 0; k0 < DIMC; k0 += 32) {
        frag8 af = ld_xfrag(xs, wm*16 + c, k0 + q*8);
        #pragma unroll
        for (int nt = 0; nt < 8; ++nt) {
            frag8 bf = *(const frag8*)(gate_wb + (size_t)(wc*128 + nt*16 + c)*DIMC + k0 + q*8);
            accg[nt] = __builtin_amdgcn_mfma_f32_16x16x32_bf16(af, bf, accg[nt], 0, 0, 0);
        }
    }
    // out GEMM (K = 128 states of u, bf16 direct)
    f32x4 acco[8] = {};
    {
        const int arow = r0 + wm*16 + c;
        for (int k0 = 0; k0 < STATE; k0 += 32) {
            frag8 af = *(const frag8*)(ub + (size_t)arow*STATE + k0 + q*8);
            #pragma unroll
            for (int nt = 0; nt < 8; ++nt) {
                frag8 bf = *(const frag8*)(out_wb + (size_t)(wc*128 + nt*16 + c)*STATE + k0 + q*8);
                acco[nt] = __builtin_amdgcn_mfma_f32_16x16x32_bf16(af, bf, acco[nt], 0, 0, 0);
            }
        }
    }
    // residual from staged x-tile (bf16) into registers, then release LDS for vbuf
    float res[8][4];
    #pragma unroll
    for (int nt = 0; nt < 8; ++nt) {
        int col = wc*128 + nt*16 + c;
        #pragma unroll
        for (int r = 0; r < 4; ++r) {
            int row = wm*16 + q*4 + r;
            res[nt][r] = __bfloat162float(xs[(size_t)row*XSTR + (col ^ ((row&3)<<3))]);
        }
    }
    __syncthreads();   // all xs reads done before vbuf overwrites

    #pragma unroll
    for (int nt = 0; nt < 8; ++nt) {
        int col = wc*128 + nt*16 + c;
        float gb = gate_b[col], ob = out_b[col];
        #pragma unroll
        for (int r = 0; r < 4; ++r) {
            float g = 1.f/(1.f + expf(-(accg[nt][r] + gb)));
            float o = acco[nt][r] + ob;
            vbuf[(wm*16 + q*4 + r)*260 + col] = g*o + res[nt][r];
        }
    }
    __syncthreads();
    {
        int rr = t >> 3, lane8 = t & 7;
        float s1 = 0.f, s2 = 0.f;
        #pragma unroll
        for (int k = 0; k < 32; ++k) {
            float v = vbuf[rr*260 + lane8 + 8*k];
            s1 += v; s2 += v*v;
        }
        s1 += __shfl_xor(s1, 1); s2 += __shfl_xor(s2, 1);
        s1 += __shfl_xor(s1, 2); s2 += __shfl_xor(s2, 2);
        s1 += __shfl_xor(s1, 4); s2 += __shfl_xor(s2, 4);
        if (lane8 == 0) {
            float mu = s1 * (1.f/256.f);
            float var = s2 * (1.f/256.f) - mu*mu;
            mus[rr] = mu;
            rstds[rr] = rsqrtf(var + LN_EPS);
        }
    }
    __syncthreads();
    {
        int cc = t;
        float g = norm_g[cc], be = norm_b[cc];
        float* outp = y + ((size_t)b*DIMC + cc)*LSEQ + l0;
        #pragma unroll
        for (int qq = 0; qq < 8; ++qq) {
            float4 v4;
            v4.x = (vbuf[(qq*4+0)*260 + cc] - mus[qq*4+0]) * rstds[qq*4+0] * g + be;
            v4.y = (vbuf[(qq*4+1)*260 + cc] - mus[qq*4+1]) * rstds[qq*4+1] * g + be;
            v4.z = (vbuf[(qq*4+2)*260 + cc] - mus[qq*4+2]) * rstds[qq*4+2] * g + be;
            v4.w = (vbuf[(qq*4+3)*260 + cc] - mus[qq*4+3]) * rstds[qq*4+3] * g + be;
            *(float4*)(outp + qq*4) = v4;
        }
    }
}

extern "C" void kernel_launch(void* const* d_in, const int* in_sizes, int n_in,
                              void* d_out, int out_size, void* d_ws, size_t ws_size,
                              hipStream_t stream) {
    const float* x      = (const float*)d_in[0];
    const float* in_w   = (const float*)d_in[1];
    const float* in_b   = (const float*)d_in[2];
    const float* U      = (const float*)d_in[3];
    const float* V      = (const float*)d_in[4];
    const float* B_w    = (const float*)d_in[5];
    const float* B_b    = (const float*)d_in[6];
    const float* out_w  = (const float*)d_in[7];
    const float* out_b  = (const float*)d_in[8];
    const float* gate_w = (const float*)d_in[9];
    const float* gate_b = (const float*)d_in[10];
    const float* norm_g = (const float*)d_in[11];
    const float* norm_b = (const float*)d_in[12];
    const float* conv_w = (const float*)d_in[13];
    const float* conv_b = (const float*)d_in[14];

    float* yfinal = (float*)d_out;                                 // [16][256][64][64]
    float* state_out = yfinal + (size_t)NBATCH*DIMC*LSEQ;          // [16][4096][128] fp32

    float* ws  = (float*)d_ws;
    float* bxu = ws;                                               // bx fp32; later u bf16 (smaller)
    __hip_bfloat16* ub = (__hip_bfloat16*)ws;
    __hip_bfloat16* Atb16  = (__hip_bfloat16*)(ws + (size_t)NROWS*STATE);
    __hip_bfloat16* in_wb  = Atb16 + STATE*STATE;
    __hip_bfloat16* B_wb   = in_wb + STATE*DIMC;
    __hip_bfloat16* gate_wb= B_wb + STATE*STATE;
    __hip_bfloat16* out_wb = gate_wb + DIMC*DIMC;

    // bf16 scan outputs live in the (later overwritten) y region of d_out
    __hip_bfloat16* ylr = (__hip_bfloat16*)yfinal;                 // NROWS*STATE bf16
    __hip_bfloat16* yrl = ylr + (size_t)NROWS*STATE;               // NROWS*STATE bf16

    a_kernel<<<dim3(STATE), dim3(STATE), 0, stream>>>(U, V, Atb16);
    prep_weights<<<dim3(256, 4), dim3(256), 0, stream>>>(in_w, B_w, gate_w, out_w,
                                                         in_wb, B_wb, gate_wb, out_wb);
    gemm_in_mfma<<<dim3(NROWS/64), dim3(256), 0, stream>>>(x, in_wb, in_b, state_out);
    gemm_B_mfma<<<dim3(NROWS/64), dim3(256), 0, stream>>>(state_out, B_wb, B_b, bxu);
    scan_mfma<<<dim3(128), dim3(64), 0, stream>>>(bxu, Atb16, ylr, yrl);
    conv_combine<<<dim3(LSEQ/8, NBATCH), dim3(128), 0, stream>>>(ylr, yrl, conv_w, conv_b, ub);
    fused_out<<<dim3(NROWS/32), dim3(256), 0, stream>>>(x, ub, out_wb, out_b, gate_wb, gate_b,
                                                        norm_g, norm_b, yfinal);
    (void)in_sizes; (void)n_in; (void)out_size; (void)ws_size;
}

// Round 5
// 272.147 us; speedup vs baseline: 2.9821x; 1.0798x over previous
//
#include <hip/hip_runtime.h>
#include <hip/hip_bf16.h>

#define DIMC 256
#define STATE 128
#define RANK 64
#define NBATCH 16
#define LSEQ 4096
#define NROWS (NBATCH*LSEQ)   // 65536
#define LN_EPS 1e-5f
#define XSTR 264              // LDS row stride (bf16 elems) for staged x tiles
#define X1STR 136             // LDS row stride for x1 transpose tile

typedef __attribute__((ext_vector_type(8))) short frag8;   // 8 bf16 (4 VGPRs)
typedef __attribute__((ext_vector_type(4))) float f32x4;   // 4 fp32

union AFrag { __hip_bfloat16 h[8]; frag8 f; };
union Pack4 { __hip_bfloat16 h[4]; uint2 u; };
union Pack8 { __hip_bfloat16 h[8]; uint4 u; };

// ---------------- At[j][i] = A[i][j] = sum_r V[i,r]*U[j,r], stored bf16 ----------------
__global__ __launch_bounds__(128) void a_kernel(const float* __restrict__ U, const float* __restrict__ V,
                                                __hip_bfloat16* __restrict__ At) {
    int i = blockIdx.x, j = threadIdx.x;
    float s = 0.f;
    #pragma unroll
    for (int r = 0; r < RANK; ++r) s += V[i*RANK + r] * U[j*RANK + r];
    At[j*STATE + i] = __float2bfloat16(s);
}

// ---------------- weights fp32 -> bf16 ----------------
__global__ __launch_bounds__(256) void prep_weights(const float* __restrict__ in_w, const float* __restrict__ B_w,
                                                    const float* __restrict__ gate_w, const float* __restrict__ out_w,
                                                    __hip_bfloat16* __restrict__ in_wb, __hip_bfloat16* __restrict__ B_wb,
                                                    __hip_bfloat16* __restrict__ gate_wb, __hip_bfloat16* __restrict__ out_wb) {
    int idx = blockIdx.x*256 + threadIdx.x;
    int which = blockIdx.y;
    if (which == 0) { if (idx < STATE*DIMC)  in_wb[idx]   = __float2bfloat16(in_w[idx]); }
    else if (which == 1) { if (idx < STATE*STATE) B_wb[idx] = __float2bfloat16(B_w[idx]); }
    else if (which == 2) { if (idx < DIMC*DIMC)  gate_wb[idx] = __float2bfloat16(gate_w[idx]); }
    else { if (idx < DIMC*STATE) out_wb[idx] = __float2bfloat16(out_w[idx]); }
}

// ---- stage x[b][0..255][l0..l0+LROWS) into LDS bf16 [l][cin^((l&3)<<3)], stride XSTR ----
template<int LROWS>
__device__ inline void stage_x_tile(const float* __restrict__ xb, int l0,
                                    __hip_bfloat16* __restrict__ xs, int t) {
    constexpr int NP = LROWS/4;
    #pragma unroll
    for (int p = 0; p < NP; ++p) {
        int cin = (t>>2) + (p&3)*64;
        int lq  = (t&3) + (p>>2)*4;
        float4 v = *(const float4*)(xb + (size_t)cin*LSEQ + l0 + lq*4);
        int lb = lq*4;
        xs[(size_t)(lb+0)*XSTR + (cin ^ 0 )] = __float2bfloat16(v.x);
        xs[(size_t)(lb+1)*XSTR + (cin ^ 8 )] = __float2bfloat16(v.y);
        xs[(size_t)(lb+2)*XSTR + (cin ^ 16)] = __float2bfloat16(v.z);
        xs[(size_t)(lb+3)*XSTR + (cin ^ 24)] = __float2bfloat16(v.w);
    }
}
__device__ inline frag8 ld_xfrag(const __hip_bfloat16* __restrict__ xs, int row, int k) {
    return *(const frag8*)(xs + (size_t)row*XSTR + (k ^ ((row&3)<<3)));
}

// ---------------- fused in_proj + B GEMM: x1 = x@Win^T+b (kept on-chip) ; bx = x1@Bw^T+b ----------------
// block = 64 l rows, 4 waves (16 rows each, full N=128). x1 round-trips through swizzled LDS transpose.
__global__ __launch_bounds__(256) void gemm_inB(const float* __restrict__ x,
                                                const __hip_bfloat16* __restrict__ in_wb, const float* __restrict__ in_b,
                                                const __hip_bfloat16* __restrict__ B_wb, const float* __restrict__ B_b,
                                                float* __restrict__ state_out, float* __restrict__ bx) {
    __shared__ __hip_bfloat16 xs[64*XSTR];                  // 33792 B; x1s aliases after first GEMM
    __hip_bfloat16* x1s = xs;                               // 64*X1STR*2 = 17408 B
    const int t = threadIdx.x;
    const int lane = t & 63;
    const int c = lane & 15, q = lane >> 4;
    const int wm = t >> 6;
    const int r0 = blockIdx.x * 64;
    const int b = r0 >> 12, l0 = r0 & 4095;

    stage_x_tile<64>(x + (size_t)b*DIMC*LSEQ, l0, xs, t);
    __syncthreads();

    // GEMM 1: x1[l][s] = sum_c x*W_in
    f32x4 acc[8] = {};
    for (int k0 = 0; k0 < DIMC; k0 += 32) {
        frag8 af = ld_xfrag(xs, wm*16 + c, k0 + q*8);
        #pragma unroll
        for (int nt = 0; nt < 8; ++nt) {
            frag8 bf = *(const frag8*)(in_wb + (size_t)(nt*16 + c)*DIMC + k0 + q*8);
            acc[nt] = __builtin_amdgcn_mfma_f32_16x16x32_bf16(af, bf, acc[nt], 0, 0, 0);
        }
    }
    __syncthreads();   // all xs reads done before x1s overwrite

    // emit x1: fp32 -> state_out (required output), bf16 -> LDS transpose (A-operand of GEMM 2)
    #pragma unroll
    for (int nt = 0; nt < 8; ++nt) {
        float bb = in_b[nt*16 + c];
        int col = nt*16 + c;
        #pragma unroll
        for (int r = 0; r < 4; ++r) {
            int row = wm*16 + q*4 + r;
            float v = acc[nt][r] + bb;
            state_out[(size_t)(r0 + row)*STATE + col] = v;
            x1s[(size_t)row*X1STR + (col ^ ((row&3)<<3))] = __float2bfloat16(v);
        }
    }
    __syncthreads();

    // GEMM 2: bx[l][s'] = sum_s x1*B_w
    f32x4 acc2[8] = {};
    for (int k0 = 0; k0 < STATE; k0 += 32) {
        int row = wm*16 + c;
        frag8 af = *(const frag8*)(x1s + (size_t)row*X1STR + ((k0 + q*8) ^ ((row&3)<<3)));
        #pragma unroll
        for (int nt = 0; nt < 8; ++nt) {
            frag8 bf = *(const frag8*)(B_wb + (size_t)(nt*16 + c)*STATE + k0 + q*8);
            acc2[nt] = __builtin_amdgcn_mfma_f32_16x16x32_bf16(af, bf, acc2[nt], 0, 0, 0);
        }
    }
    const int orow = r0 + wm*16 + q*4;
    #pragma unroll
    for (int nt = 0; nt < 8; ++nt) {
        float bb = B_b[nt*16 + c];
        #pragma unroll
        for (int r = 0; r < 4; ++r)
            bx[(size_t)(orow + r)*STATE + nt*16 + c] = acc2[nt][r] + bb;
    }
}

// ---------------- MFMA batched scan: 16 scans per wave; y outputs bf16 ----------------
#define HSTRIDE 144
__global__ __launch_bounds__(64, 1) void scan_mfma(const float* __restrict__ bx,
                                                   const __hip_bfloat16* __restrict__ At,
                                                   __hip_bfloat16* __restrict__ ylr,
                                                   __hip_bfloat16* __restrict__ yrl) {
    __shared__ __hip_bfloat16 Hb[16 * HSTRIDE];
    const int l = threadIdx.x;
    const int c = l & 15;
    const int q = l >> 4;

    const int S   = blockIdx.x * 16 + c;
    const int dir = S >> 10;
    const int b   = (S >> 6) & 15;
    const int blk = S & 63;
    const int lp0 = blk * 64;
    const int lorig0 = dir ? (LSEQ - 1 - lp0) : lp0;
    const int sgnstep = dir ? -STATE : STATE;

    const float* bxrow = bx + ((size_t)b*LSEQ + lorig0)*STATE;
    __hip_bfloat16* yrow = (dir ? yrl : ylr) + ((size_t)b*LSEQ + lp0)*STATE;

    frag8 afr[8][4];
    #pragma unroll
    for (int m = 0; m < 8; ++m)
        #pragma unroll
        for (int kc = 0; kc < 4; ++kc)
            afr[m][kc] = *(const frag8*)(At + (size_t)(m*16 + c)*STATE + kc*32 + q*8);

    for (int k = l; k < 16*HSTRIDE; k += 64) Hb[k] = __float2bfloat16(0.f);
    __syncthreads();

    f32x4 pf[8];
    #pragma unroll
    for (int m = 0; m < 8; ++m)
        pf[m] = *(const f32x4*)(bxrow + m*16 + q*4);

    for (int t = 0; t < 64; ++t) {
        frag8 bfr[4];
        #pragma unroll
        for (int kc = 0; kc < 4; ++kc)
            bfr[kc] = *(const frag8*)(&Hb[c*HSTRIDE + kc*32 + q*8]);

        f32x4 acc[8];
        #pragma unroll
        for (int m = 0; m < 8; ++m) {
            f32x4 a = {0.f, 0.f, 0.f, 0.f};
            #pragma unroll
            for (int kc = 0; kc < 4; ++kc)
                a = __builtin_amdgcn_mfma_f32_16x16x32_bf16(afr[m][kc], bfr[kc], a, 0, 0, 0);
            acc[m] = a;
        }

        #pragma unroll
        for (int m = 0; m < 8; ++m) acc[m] += pf[m];
        if (t < 63) {
            bxrow += sgnstep;
            #pragma unroll
            for (int m = 0; m < 8; ++m)
                pf[m] = *(const f32x4*)(bxrow + m*16 + q*4);
        }

        Pack4 pk[8];
        #pragma unroll
        for (int m = 0; m < 8; ++m) {
            pk[m].h[0] = __float2bfloat16(acc[m][0]);
            pk[m].h[1] = __float2bfloat16(acc[m][1]);
            pk[m].h[2] = __float2bfloat16(acc[m][2]);
            pk[m].h[3] = __float2bfloat16(acc[m][3]);
        }
        #pragma unroll
        for (int m = 0; m < 8; ++m)
            *(uint2*)(yrow + m*16 + q*4) = pk[m].u;
        yrow += STATE;

        __syncthreads();
        #pragma unroll
        for (int m = 0; m < 8; ++m)
            *(uint2*)(&Hb[c*HSTRIDE + m*16 + q*4]) = pk[m].u;
        __syncthreads();
    }
}

// ---------------- conv7 + combine: u = 0.5*(conv(ylr)+rev(conv(yrl))) + conv_b, bf16 io ----------------
__global__ __launch_bounds__(128) void conv_combine(const __hip_bfloat16* __restrict__ ylr,
                                                    const __hip_bfloat16* __restrict__ yrl,
                                                    const float* __restrict__ conv_w, const float* __restrict__ conv_b,
                                                    __hip_bfloat16* __restrict__ u) {
    const int t = threadIdx.x;
    const int s8 = (t & 15) * 8;
    const int l = blockIdx.x * 8 + (t >> 4);
    const int b = blockIdx.y;

    float wv[8][7];
    #pragma unroll
    for (int j = 0; j < 8; ++j)
        #pragma unroll
        for (int i = 0; i < 7; ++i) wv[j][i] = conv_w[(s8+j)*7 + i];

    const __hip_bfloat16* plr = ylr + (size_t)b*LSEQ*STATE;
    const __hip_bfloat16* prl = yrl + (size_t)b*LSEQ*STATE;

    float acc[8];
    {
        Pack8 v; v.u = *(const uint4*)(plr + (size_t)l*STATE + s8);
        #pragma unroll
        for (int j = 0; j < 8; ++j) acc[j] = __bfloat162float(v.h[j]);
    }
    #pragma unroll
    for (int i = 0; i < 7; ++i) {
        int qq = l - 3 + i;
        if (qq >= 0 && qq < LSEQ) {
            Pack8 v; v.u = *(const uint4*)(plr + (size_t)qq*STATE + s8);
            #pragma unroll
            for (int j = 0; j < 8; ++j) acc[j] += wv[j][i] * __bfloat162float(v.h[j]);
        }
    }
    const int lp = LSEQ - 1 - l;
    {
        Pack8 v; v.u = *(const uint4*)(prl + (size_t)lp*STATE + s8);
        #pragma unroll
        for (int j = 0; j < 8; ++j) acc[j] += __bfloat162float(v.h[j]);
    }
    #pragma unroll
    for (int i = 0; i < 7; ++i) {
        int qq = lp - 3 + i;
        if (qq >= 0 && qq < LSEQ) {
            Pack8 v; v.u = *(const uint4*)(prl + (size_t)qq*STATE + s8);
            #pragma unroll
            for (int j = 0; j < 8; ++j) acc[j] += wv[j][i] * __bfloat162float(v.h[j]);
        }
    }
    Pack8 o;
    #pragma unroll
    for (int j = 0; j < 8; ++j) o.h[j] = __float2bfloat16(0.5f*acc[j] + conv_b[s8+j]);
    *(uint4*)(u + ((size_t)b*LSEQ + l)*STATE + s8) = o.u;
}

// ---------------- fused MFMA: gate GEMM + out GEMM + sigmoid*o + residual + LN + direct transposed store ----
// block = 32 l x 256 c; 4 waves in 2(M) x 2(N). All epilogue in registers; LN via shfl + 512B LDS.
__global__ __launch_bounds__(256) void fused_out(const float* __restrict__ x, const __hip_bfloat16* __restrict__ ub,
    const __hip_bfloat16* __restrict__ out_wb, const float* __restrict__ out_b,
    const __hip_bfloat16* __restrict__ gate_wb, const float* __restrict__ gate_b,
    const float* __restrict__ norm_g, const float* __restrict__ norm_b,
    float* __restrict__ y) {
    __shared__ __hip_bfloat16 xs[32*XSTR];         // 16896 B
    __shared__ float lnbuf[2][2][16][2];           // [wm][wc][row16][s1,s2]
    const int t = threadIdx.x;
    const int lane = t & 63, c = lane & 15, q = lane >> 4;
    const int w = t >> 6, wm = w >> 1, wc = w & 1;
    const int r0 = blockIdx.x * 32;
    const int b = r0 >> 12, l0 = r0 & 4095;

    stage_x_tile<32>(x + (size_t)b*DIMC*LSEQ, l0, xs, t);
    __syncthreads();

    // gate GEMM (K = 256 channels of x, A from LDS)
    f32x4 accg[8] = {};
    for (int k0 = 0; k0 < DIMC; k0 += 32) {
        frag8 af = ld_xfrag(xs, wm*16 + c, k0 + q*8);
        #pragma unroll
        for (int nt = 0; nt < 8; ++nt) {
            frag8 bf = *(const frag8*)(gate_wb + (size_t)(wc*128 + nt*16 + c)*DIMC + k0 + q*8);
            accg[nt] = __builtin_amdgcn_mfma_f32_16x16x32_bf16(af, bf, accg[nt], 0, 0, 0);
        }
    }
    // out GEMM (K = 128 states of u, bf16 direct from global)
    f32x4 acco[8] = {};
    {
        const int arow = r0 + wm*16 + c;
        for (int k0 = 0; k0 < STATE; k0 += 32) {
            frag8 af = *(const frag8*)(ub + (size_t)arow*STATE + k0 + q*8);
            #pragma unroll
            for (int nt = 0; nt < 8; ++nt) {
                frag8 bf = *(const frag8*)(out_wb + (size_t)(wc*128 + nt*16 + c)*STATE + k0 + q*8);
                acco[nt] = __builtin_amdgcn_mfma_f32_16x16x32_bf16(af, bf, acco[nt], 0, 0, 0);
            }
        }
    }
    // epilogue in registers: v = sigmoid(gate)*o + residual(from xs); accumulate LN partials
    float s1[4] = {0.f,0.f,0.f,0.f}, s2[4] = {0.f,0.f,0.f,0.f};
    #pragma unroll
    for (int nt = 0; nt < 8; ++nt) {
        int col = wc*128 + nt*16 + c;
        float gb = gate_b[col], ob = out_b[col];
        #pragma unroll
        for (int r = 0; r < 4; ++r) {
            int row = wm*16 + q*4 + r;
            float res = __bfloat162float(xs[(size_t)row*XSTR + (col ^ ((row&3)<<3))]);
            float g = 1.f/(1.f + expf(-(accg[nt][r] + gb)));
            float v = g*(acco[nt][r] + ob) + res;
            accg[nt][r] = v;                       // reuse accg as v storage
            s1[r] += v; s2[r] += v*v;
        }
    }
    // reduce across the 16 c-lanes (same q group)
    #pragma unroll
    for (int m = 1; m <= 8; m <<= 1) {
        #pragma unroll
        for (int r = 0; r < 4; ++r) {
            s1[r] += __shfl_xor(s1[r], m);
            s2[r] += __shfl_xor(s2[r], m);
        }
    }
    if (c == 0) {
        #pragma unroll
        for (int r = 0; r < 4; ++r) {
            lnbuf[wm][wc][q*4 + r][0] = s1[r];
            lnbuf[wm][wc][q*4 + r][1] = s2[r];
        }
    }
    __syncthreads();
    float mu[4], rstd[4];
    #pragma unroll
    for (int r = 0; r < 4; ++r) {
        int row16 = q*4 + r;
        float t1 = lnbuf[wm][0][row16][0] + lnbuf[wm][1][row16][0];
        float t2 = lnbuf[wm][0][row16][1] + lnbuf[wm][1][row16][1];
        float m_ = t1 * (1.f/256.f);
        mu[r] = m_;
        rstd[r] = rsqrtf(t2 * (1.f/256.f) - m_*m_ + LN_EPS);
    }
    // direct transposed store: lane owns 4 consecutive l for each of its 8 channels
    #pragma unroll
    for (int nt = 0; nt < 8; ++nt) {
        int col = wc*128 + nt*16 + c;
        float g = norm_g[col], be = norm_b[col];
        float4 v4;
        v4.x = (accg[nt][0] - mu[0]) * rstd[0] * g + be;
        v4.y = (accg[nt][1] - mu[1]) * rstd[1] * g + be;
        v4.z = (accg[nt][2] - mu[2]) * rstd[2] * g + be;
        v4.w = (accg[nt][3] - mu[3]) * rstd[3] * g + be;
        *(float4*)(y + ((size_t)b*DIMC + col)*LSEQ + l0 + wm*16 + q*4) = v4;
    }
}

extern "C" void kernel_launch(void* const* d_in, const int* in_sizes, int n_in,
                              void* d_out, int out_size, void* d_ws, size_t ws_size,
                              hipStream_t stream) {
    const float* x      = (const float*)d_in[0];
    const float* in_w   = (const float*)d_in[1];
    const float* in_b   = (const float*)d_in[2];
    const float* U      = (const float*)d_in[3];
    const float* V      = (const float*)d_in[4];
    const float* B_w    = (const float*)d_in[5];
    const float* B_b    = (const float*)d_in[6];
    const float* out_w  = (const float*)d_in[7];
    const float* out_b  = (const float*)d_in[8];
    const float* gate_w = (const float*)d_in[9];
    const float* gate_b = (const float*)d_in[10];
    const float* norm_g = (const float*)d_in[11];
    const float* norm_b = (const float*)d_in[12];
    const float* conv_w = (const float*)d_in[13];
    const float* conv_b = (const float*)d_in[14];

    float* yfinal = (float*)d_out;                                 // [16][256][64][64]
    float* state_out = yfinal + (size_t)NBATCH*DIMC*LSEQ;          // [16][4096][128] fp32

    float* ws  = (float*)d_ws;
    float* bxu = ws;                                               // bx fp32; later u bf16
    __hip_bfloat16* ub = (__hip_bfloat16*)ws;
    __hip_bfloat16* Atb16  = (__hip_bfloat16*)(ws + (size_t)NROWS*STATE);
    __hip_bfloat16* in_wb  = Atb16 + STATE*STATE;
    __hip_bfloat16* B_wb   = in_wb + STATE*DIMC;
    __hip_bfloat16* gate_wb= B_wb + STATE*STATE;
    __hip_bfloat16* out_wb = gate_wb + DIMC*DIMC;

    // bf16 scan outputs live in the (later overwritten) y region of d_out
    __hip_bfloat16* ylr = (__hip_bfloat16*)yfinal;                 // NROWS*STATE bf16
    __hip_bfloat16* yrl = ylr + (size_t)NROWS*STATE;               // NROWS*STATE bf16

    a_kernel<<<dim3(STATE), dim3(STATE), 0, stream>>>(U, V, Atb16);
    prep_weights<<<dim3(256, 4), dim3(256), 0, stream>>>(in_w, B_w, gate_w, out_w,
                                                         in_wb, B_wb, gate_wb, out_wb);
    gemm_inB<<<dim3(NROWS/64), dim3(256), 0, stream>>>(x, in_wb, in_b, B_wb, B_b, state_out, bxu);
    scan_mfma<<<dim3(128), dim3(64), 0, stream>>>(bxu, Atb16, ylr, yrl);
    conv_combine<<<dim3(LSEQ/8, NBATCH), dim3(128), 0, stream>>>(ylr, yrl, conv_w, conv_b, ub);
    fused_out<<<dim3(NROWS/32), dim3(256), 0, stream>>>(x, ub, out_wb, out_b, gate_wb, gate_b,
                                                        norm_g, norm_b, yfinal);
    (void)in_sizes; (void)n_in; (void)out_size; (void)ws_size;
}

// Round 6
// 158.123 us; speedup vs baseline: 5.1324x; 1.7211x over previous
//
#include <hip/hip_runtime.h>
#include <hip/hip_bf16.h>

#define DIMC 256
#define STATE 128
#define RANK 64
#define NBATCH 16
#define LSEQ 4096
#define NROWS (NBATCH*LSEQ)   // 65536
#define LN_EPS 1e-5f
#define XSTR 264              // LDS row stride (bf16 elems) for staged x tiles
#define X1STR 136             // LDS row stride for x1 transpose tile

typedef __attribute__((ext_vector_type(8))) short frag8;   // 8 bf16 (4 VGPRs)
typedef __attribute__((ext_vector_type(4))) float f32x4;   // 4 fp32

union AFrag { __hip_bfloat16 h[8]; frag8 f; };
union Pack4 { __hip_bfloat16 h[4]; uint2 u; };
union Pack8 { __hip_bfloat16 h[8]; uint4 u; };

__device__ inline void gload_lds16(const void* g, void* l) {
    __builtin_amdgcn_global_load_lds((const __attribute__((address_space(1))) void*)g,
                                     (__attribute__((address_space(3))) void*)l, 16, 0, 0);
}

// Stage a [nrows][32-k] bf16 weight slice into LDS linear [row][64B] via global_load_lds.
// Global source pre-swizzled (col ^= (row>>1)&3) so b128 frag reads are 2-way (free).
__device__ inline void stage_wslice(const __hip_bfloat16* __restrict__ W, int Krow, int k0,
                                    __hip_bfloat16* dst, int t, int nrows) {
    const int lane = t & 63, w = t >> 6;
    const int rounds = nrows >> 6;             // 2 for 128 rows, 4 for 256
    for (int j = 0; j < rounds; ++j) {
        int base = (w*rounds + j) << 10;       // wave-uniform byte base in slice
        int X = base + lane*16;
        int r = X >> 6;
        int cg = (X >> 4) & 3;
        const __hip_bfloat16* src = W + (size_t)r*Krow + k0 + ((cg ^ ((r>>1)&3)) << 3);
        gload_lds16(src, (char*)dst + base);
    }
}
__device__ inline frag8 ld_wfrag(const __hip_bfloat16* buf, int row, int q) {
    return *(const frag8*)((const char*)buf + (row<<6) + ((q ^ ((row>>1)&3))<<4));
}

// ---------------- At[j][i] = A[i][j] = sum_r V[i,r]*U[j,r], stored bf16 ----------------
__global__ __launch_bounds__(128) void a_kernel(const float* __restrict__ U, const float* __restrict__ V,
                                                __hip_bfloat16* __restrict__ At) {
    int i = blockIdx.x, j = threadIdx.x;
    float s = 0.f;
    #pragma unroll
    for (int r = 0; r < RANK; ++r) s += V[i*RANK + r] * U[j*RANK + r];
    At[j*STATE + i] = __float2bfloat16(s);
}

// ---------------- weights fp32 -> bf16 ----------------
__global__ __launch_bounds__(256) void prep_weights(const float* __restrict__ in_w, const float* __restrict__ B_w,
                                                    const float* __restrict__ gate_w, const float* __restrict__ out_w,
                                                    __hip_bfloat16* __restrict__ in_wb, __hip_bfloat16* __restrict__ B_wb,
                                                    __hip_bfloat16* __restrict__ gate_wb, __hip_bfloat16* __restrict__ out_wb) {
    int idx = blockIdx.x*256 + threadIdx.x;
    int which = blockIdx.y;
    if (which == 0) { if (idx < STATE*DIMC)  in_wb[idx]   = __float2bfloat16(in_w[idx]); }
    else if (which == 1) { if (idx < STATE*STATE) B_wb[idx] = __float2bfloat16(B_w[idx]); }
    else if (which == 2) { if (idx < DIMC*DIMC)  gate_wb[idx] = __float2bfloat16(gate_w[idx]); }
    else { if (idx < DIMC*STATE) out_wb[idx] = __float2bfloat16(out_w[idx]); }
}

// ---- stage x[b][0..255][l0..l0+LROWS) into LDS bf16 [l][cin^((l&3)<<3)], stride XSTR ----
template<int LROWS>
__device__ inline void stage_x_tile(const float* __restrict__ xb, int l0,
                                    __hip_bfloat16* __restrict__ xs, int t) {
    constexpr int NP = LROWS/4;
    #pragma unroll
    for (int p = 0; p < NP; ++p) {
        int cin = (t>>2) + (p&3)*64;
        int lq  = (t&3) + (p>>2)*4;
        float4 v = *(const float4*)(xb + (size_t)cin*LSEQ + l0 + lq*4);
        int lb = lq*4;
        xs[(size_t)(lb+0)*XSTR + (cin ^ 0 )] = __float2bfloat16(v.x);
        xs[(size_t)(lb+1)*XSTR + (cin ^ 8 )] = __float2bfloat16(v.y);
        xs[(size_t)(lb+2)*XSTR + (cin ^ 16)] = __float2bfloat16(v.z);
        xs[(size_t)(lb+3)*XSTR + (cin ^ 24)] = __float2bfloat16(v.w);
    }
}
__device__ inline frag8 ld_xfrag(const __hip_bfloat16* __restrict__ xs, int row, int k) {
    return *(const frag8*)(xs + (size_t)row*XSTR + (k ^ ((row&3)<<3)));
}

// ---------------- fused in_proj + B GEMM with LDS-staged dbuf weights ----------------
// block = 64 l rows, 4 waves (16 rows each, full N=128).
__global__ __launch_bounds__(256) void gemm_inB(const float* __restrict__ x,
                                                const __hip_bfloat16* __restrict__ in_wb, const float* __restrict__ in_b,
                                                const __hip_bfloat16* __restrict__ B_wb, const float* __restrict__ B_b,
                                                float* __restrict__ state_out, float* __restrict__ bx) {
    __shared__ __hip_bfloat16 xs[64*XSTR];                  // 33792 B; x1s aliases after GEMM1
    __shared__ __hip_bfloat16 wsl[2][4096];                 // 2 x 8192 B weight slices
    __hip_bfloat16* x1s = xs;
    const int t = threadIdx.x;
    const int lane = t & 63;
    const int c = lane & 15, q = lane >> 4;
    const int wm = t >> 6;
    const int r0 = blockIdx.x * 64;
    const int b = r0 >> 12, l0 = r0 & 4095;

    stage_x_tile<64>(x + (size_t)b*DIMC*LSEQ, l0, xs, t);
    stage_wslice(in_wb, DIMC, 0, wsl[0], t, STATE);
    __syncthreads();

    // GEMM 1: x1[l][s] = sum_c x*W_in  (8 k-slices, dbuf)
    f32x4 acc[8] = {};
    #pragma unroll
    for (int i = 0; i < 8; ++i) {
        if (i < 7) stage_wslice(in_wb, DIMC, (i+1)*32, wsl[(i+1)&1], t, STATE);
        frag8 af = ld_xfrag(xs, wm*16 + c, i*32 + q*8);
        #pragma unroll
        for (int nt = 0; nt < 8; ++nt) {
            frag8 bf = ld_wfrag(wsl[i&1], nt*16 + c, q);
            acc[nt] = __builtin_amdgcn_mfma_f32_16x16x32_bf16(af, bf, acc[nt], 0, 0, 0);
        }
        __syncthreads();
    }

    stage_wslice(B_wb, STATE, 0, wsl[0], t, STATE);   // prologue for GEMM2 (wsl[0] free)

    // emit x1: fp32 -> state_out, bf16 -> swizzled LDS transpose
    #pragma unroll
    for (int nt = 0; nt < 8; ++nt) {
        float bb = in_b[nt*16 + c];
        int col = nt*16 + c;
        #pragma unroll
        for (int r = 0; r < 4; ++r) {
            int row = wm*16 + q*4 + r;
            float v = acc[nt][r] + bb;
            state_out[(size_t)(r0 + row)*STATE + col] = v;
            x1s[(size_t)row*X1STR + (col ^ ((row&3)<<3))] = __float2bfloat16(v);
        }
    }
    __syncthreads();

    // GEMM 2: bx[l][s'] = sum_s x1*B_w  (4 k-slices, dbuf)
    f32x4 acc2[8] = {};
    #pragma unroll
    for (int i = 0; i < 4; ++i) {
        if (i < 3) stage_wslice(B_wb, STATE, (i+1)*32, wsl[(i+1)&1], t, STATE);
        int row = wm*16 + c;
        frag8 af = *(const frag8*)(x1s + (size_t)row*X1STR + (((i*32) + q*8) ^ ((row&3)<<3)));
        #pragma unroll
        for (int nt = 0; nt < 8; ++nt) {
            frag8 bf = ld_wfrag(wsl[i&1], nt*16 + c, q);
            acc2[nt] = __builtin_amdgcn_mfma_f32_16x16x32_bf16(af, bf, acc2[nt], 0, 0, 0);
        }
        __syncthreads();
    }
    const int orow = r0 + wm*16 + q*4;
    #pragma unroll
    for (int nt = 0; nt < 8; ++nt) {
        float bb = B_b[nt*16 + c];
        #pragma unroll
        for (int r = 0; r < 4; ++r)
            bx[(size_t)(orow + r)*STATE + nt*16 + c] = acc2[nt][r] + bb;
    }
}

// ---------------- MFMA batched scan: 16 scans/block, 4 waves (32 state rows each) ----------------
#define HSTRIDE 144
__global__ __launch_bounds__(256, 1) void scan_mfma(const float* __restrict__ bx,
                                                    const __hip_bfloat16* __restrict__ At,
                                                    __hip_bfloat16* __restrict__ ylr,
                                                    __hip_bfloat16* __restrict__ yrl) {
    __shared__ __hip_bfloat16 Hb[16 * HSTRIDE];
    const int t = threadIdx.x;
    const int l = t & 63;
    const int wm = t >> 6;          // wave owns state rows wm*32 .. wm*32+31 (tiles 2wm, 2wm+1)
    const int c = l & 15;
    const int q = l >> 4;

    const int S   = blockIdx.x * 16 + c;
    const int dir = S >> 10;
    const int b   = (S >> 6) & 15;
    const int blk = S & 63;
    const int lp0 = blk * 64;
    const int lorig0 = dir ? (LSEQ - 1 - lp0) : lp0;
    const int sgnstep = dir ? -STATE : STATE;

    const float* bxrow = bx + ((size_t)b*LSEQ + lorig0)*STATE;
    __hip_bfloat16* yrow = (dir ? yrl : ylr) + ((size_t)b*LSEQ + lp0)*STATE;

    frag8 afr[2][4];
    #pragma unroll
    for (int mm = 0; mm < 2; ++mm)
        #pragma unroll
        for (int kc = 0; kc < 4; ++kc)
            afr[mm][kc] = *(const frag8*)(At + (size_t)((wm*2+mm)*16 + c)*STATE + kc*32 + q*8);

    for (int k = t; k < 16*HSTRIDE; k += 256) Hb[k] = __float2bfloat16(0.f);
    __syncthreads();

    f32x4 pf[2];
    #pragma unroll
    for (int mm = 0; mm < 2; ++mm)
        pf[mm] = *(const f32x4*)(bxrow + (wm*2+mm)*16 + q*4);

    for (int tt = 0; tt < 64; ++tt) {
        frag8 bfr[4];
        #pragma unroll
        for (int kc = 0; kc < 4; ++kc)
            bfr[kc] = *(const frag8*)(&Hb[c*HSTRIDE + kc*32 + q*8]);

        f32x4 acc[2];
        #pragma unroll
        for (int mm = 0; mm < 2; ++mm) {
            f32x4 a = {0.f, 0.f, 0.f, 0.f};
            #pragma unroll
            for (int kc = 0; kc < 4; ++kc)
                a = __builtin_amdgcn_mfma_f32_16x16x32_bf16(afr[mm][kc], bfr[kc], a, 0, 0, 0);
            acc[mm] = a + pf[mm];
        }
        if (tt < 63) {
            bxrow += sgnstep;
            #pragma unroll
            for (int mm = 0; mm < 2; ++mm)
                pf[mm] = *(const f32x4*)(bxrow + (wm*2+mm)*16 + q*4);
        }

        Pack4 pk[2];
        #pragma unroll
        for (int mm = 0; mm < 2; ++mm) {
            pk[mm].h[0] = __float2bfloat16(acc[mm][0]);
            pk[mm].h[1] = __float2bfloat16(acc[mm][1]);
            pk[mm].h[2] = __float2bfloat16(acc[mm][2]);
            pk[mm].h[3] = __float2bfloat16(acc[mm][3]);
        }
        #pragma unroll
        for (int mm = 0; mm < 2; ++mm)
            *(uint2*)(yrow + (wm*2+mm)*16 + q*4) = pk[mm].u;
        yrow += STATE;

        __syncthreads();   // all H reads done
        #pragma unroll
        for (int mm = 0; mm < 2; ++mm)
            *(uint2*)(&Hb[c*HSTRIDE + (wm*2+mm)*16 + q*4]) = pk[mm].u;
        __syncthreads();   // H updated
    }
}

// ---------------- conv7 + combine: u = 0.5*(conv(ylr)+rev(conv(yrl))) + conv_b, bf16 io ----------------
__global__ __launch_bounds__(128) void conv_combine(const __hip_bfloat16* __restrict__ ylr,
                                                    const __hip_bfloat16* __restrict__ yrl,
                                                    const float* __restrict__ conv_w, const float* __restrict__ conv_b,
                                                    __hip_bfloat16* __restrict__ u) {
    const int t = threadIdx.x;
    const int s8 = (t & 15) * 8;
    const int l = blockIdx.x * 8 + (t >> 4);
    const int b = blockIdx.y;

    float wv[8][7];
    #pragma unroll
    for (int j = 0; j < 8; ++j)
        #pragma unroll
        for (int i = 0; i < 7; ++i) wv[j][i] = conv_w[(s8+j)*7 + i];

    const __hip_bfloat16* plr = ylr + (size_t)b*LSEQ*STATE;
    const __hip_bfloat16* prl = yrl + (size_t)b*LSEQ*STATE;

    float acc[8];
    {
        Pack8 v; v.u = *(const uint4*)(plr + (size_t)l*STATE + s8);
        #pragma unroll
        for (int j = 0; j < 8; ++j) acc[j] = __bfloat162float(v.h[j]);
    }
    #pragma unroll
    for (int i = 0; i < 7; ++i) {
        int qq = l - 3 + i;
        if (qq >= 0 && qq < LSEQ) {
            Pack8 v; v.u = *(const uint4*)(plr + (size_t)qq*STATE + s8);
            #pragma unroll
            for (int j = 0; j < 8; ++j) acc[j] += wv[j][i] * __bfloat162float(v.h[j]);
        }
    }
    const int lp = LSEQ - 1 - l;
    {
        Pack8 v; v.u = *(const uint4*)(prl + (size_t)lp*STATE + s8);
        #pragma unroll
        for (int j = 0; j < 8; ++j) acc[j] += __bfloat162float(v.h[j]);
    }
    #pragma unroll
    for (int i = 0; i < 7; ++i) {
        int qq = lp - 3 + i;
        if (qq >= 0 && qq < LSEQ) {
            Pack8 v; v.u = *(const uint4*)(prl + (size_t)qq*STATE + s8);
            #pragma unroll
            for (int j = 0; j < 8; ++j) acc[j] += wv[j][i] * __bfloat162float(v.h[j]);
        }
    }
    Pack8 o;
    #pragma unroll
    for (int j = 0; j < 8; ++j) o.h[j] = __float2bfloat16(0.5f*acc[j] + conv_b[s8+j]);
    *(uint4*)(u + ((size_t)b*LSEQ + l)*STATE + s8) = o.u;
}

// ---------------- fused MFMA: gate+out GEMM (LDS-staged dbuf weights) + epilogue ----------------
// block = 32 l x 256 c; 4 waves in 2(M) x 2(N).
__global__ __launch_bounds__(256) void fused_out(const float* __restrict__ x, const __hip_bfloat16* __restrict__ ub,
    const __hip_bfloat16* __restrict__ out_wb, const float* __restrict__ out_b,
    const __hip_bfloat16* __restrict__ gate_wb, const float* __restrict__ gate_b,
    const float* __restrict__ norm_g, const float* __restrict__ norm_b,
    float* __restrict__ y) {
    __shared__ __hip_bfloat16 xs[32*XSTR];         // 16896 B
    __shared__ __hip_bfloat16 wsl[2][8192];        // 2 x 16384 B weight slices (256 rows)
    __shared__ float lnbuf[2][2][16][2];
    const int t = threadIdx.x;
    const int lane = t & 63, c = lane & 15, q = lane >> 4;
    const int w = t >> 6, wm = w >> 1, wc = w & 1;
    const int r0 = blockIdx.x * 32;
    const int b = r0 >> 12, l0 = r0 & 4095;

    stage_x_tile<32>(x + (size_t)b*DIMC*LSEQ, l0, xs, t);
    // u A-frags prefetched to registers (latency hidden under gate GEMM)
    frag8 ufr[4];
    {
        const int arow = r0 + wm*16 + c;
        #pragma unroll
        for (int kc = 0; kc < 4; ++kc)
            ufr[kc] = *(const frag8*)(ub + (size_t)arow*STATE + kc*32 + q*8);
    }
    stage_wslice(gate_wb, DIMC, 0, wsl[0], t, DIMC);
    __syncthreads();

    f32x4 accg[8] = {};
    f32x4 acco[8] = {};
    #pragma unroll
    for (int i = 0; i < 12; ++i) {
        if (i < 11) {
            if (i < 7) stage_wslice(gate_wb, DIMC, (i+1)*32, wsl[(i+1)&1], t, DIMC);
            else       stage_wslice(out_wb,  STATE, (i-7)*32, wsl[(i+1)&1], t, DIMC);
        }
        if (i < 8) {
            frag8 af = ld_xfrag(xs, wm*16 + c, i*32 + q*8);
            #pragma unroll
            for (int nt = 0; nt < 8; ++nt) {
                frag8 bf = ld_wfrag(wsl[i&1], wc*128 + nt*16 + c, q);
                accg[nt] = __builtin_amdgcn_mfma_f32_16x16x32_bf16(af, bf, accg[nt], 0, 0, 0);
            }
        } else {
            frag8 af = ufr[i-8];
            #pragma unroll
            for (int nt = 0; nt < 8; ++nt) {
                frag8 bf = ld_wfrag(wsl[i&1], wc*128 + nt*16 + c, q);
                acco[nt] = __builtin_amdgcn_mfma_f32_16x16x32_bf16(af, bf, acco[nt], 0, 0, 0);
            }
        }
        __syncthreads();
    }

    // epilogue in registers: v = sigmoid(gate)*o + residual(from xs); LN partials
    float s1[4] = {0.f,0.f,0.f,0.f}, s2[4] = {0.f,0.f,0.f,0.f};
    #pragma unroll
    for (int nt = 0; nt < 8; ++nt) {
        int col = wc*128 + nt*16 + c;
        float gb = gate_b[col], ob = out_b[col];
        #pragma unroll
        for (int r = 0; r < 4; ++r) {
            int row = wm*16 + q*4 + r;
            float res = __bfloat162float(xs[(size_t)row*XSTR + (col ^ ((row&3)<<3))]);
            float g = 1.f/(1.f + expf(-(accg[nt][r] + gb)));
            float v = g*(acco[nt][r] + ob) + res;
            accg[nt][r] = v;
            s1[r] += v; s2[r] += v*v;
        }
    }
    #pragma unroll
    for (int m = 1; m <= 8; m <<= 1) {
        #pragma unroll
        for (int r = 0; r < 4; ++r) {
            s1[r] += __shfl_xor(s1[r], m);
            s2[r] += __shfl_xor(s2[r], m);
        }
    }
    if (c == 0) {
        #pragma unroll
        for (int r = 0; r < 4; ++r) {
            lnbuf[wm][wc][q*4 + r][0] = s1[r];
            lnbuf[wm][wc][q*4 + r][1] = s2[r];
        }
    }
    __syncthreads();
    float mu[4], rstd[4];
    #pragma unroll
    for (int r = 0; r < 4; ++r) {
        int row16 = q*4 + r;
        float t1 = lnbuf[wm][0][row16][0] + lnbuf[wm][1][row16][0];
        float t2 = lnbuf[wm][0][row16][1] + lnbuf[wm][1][row16][1];
        float m_ = t1 * (1.f/256.f);
        mu[r] = m_;
        rstd[r] = rsqrtf(t2 * (1.f/256.f) - m_*m_ + LN_EPS);
    }
    #pragma unroll
    for (int nt = 0; nt < 8; ++nt) {
        int col = wc*128 + nt*16 + c;
        float g = norm_g[col], be = norm_b[col];
        float4 v4;
        v4.x = (accg[nt][0] - mu[0]) * rstd[0] * g + be;
        v4.y = (accg[nt][1] - mu[1]) * rstd[1] * g + be;
        v4.z = (accg[nt][2] - mu[2]) * rstd[2] * g + be;
        v4.w = (accg[nt][3] - mu[3]) * rstd[3] * g + be;
        *(float4*)(y + ((size_t)b*DIMC + col)*LSEQ + l0 + wm*16 + q*4) = v4;
    }
}

extern "C" void kernel_launch(void* const* d_in, const int* in_sizes, int n_in,
                              void* d_out, int out_size, void* d_ws, size_t ws_size,
                              hipStream_t stream) {
    const float* x      = (const float*)d_in[0];
    const float* in_w   = (const float*)d_in[1];
    const float* in_b   = (const float*)d_in[2];
    const float* U      = (const float*)d_in[3];
    const float* V      = (const float*)d_in[4];
    const float* B_w    = (const float*)d_in[5];
    const float* B_b    = (const float*)d_in[6];
    const float* out_w  = (const float*)d_in[7];
    const float* out_b  = (const float*)d_in[8];
    const float* gate_w = (const float*)d_in[9];
    const float* gate_b = (const float*)d_in[10];
    const float* norm_g = (const float*)d_in[11];
    const float* norm_b = (const float*)d_in[12];
    const float* conv_w = (const float*)d_in[13];
    const float* conv_b = (const float*)d_in[14];

    float* yfinal = (float*)d_out;                                 // [16][256][64][64]
    float* state_out = yfinal + (size_t)NBATCH*DIMC*LSEQ;          // [16][4096][128] fp32

    float* ws  = (float*)d_ws;
    float* bxu = ws;                                               // bx fp32; later u bf16
    __hip_bfloat16* ub = (__hip_bfloat16*)ws;
    __hip_bfloat16* Atb16  = (__hip_bfloat16*)(ws + (size_t)NROWS*STATE);
    __hip_bfloat16* in_wb  = Atb16 + STATE*STATE;
    __hip_bfloat16* B_wb   = in_wb + STATE*DIMC;
    __hip_bfloat16* gate_wb= B_wb + STATE*STATE;
    __hip_bfloat16* out_wb = gate_wb + DIMC*DIMC;

    // bf16 scan outputs live in the (later overwritten) y region of d_out
    __hip_bfloat16* ylr = (__hip_bfloat16*)yfinal;                 // NROWS*STATE bf16
    __hip_bfloat16* yrl = ylr + (size_t)NROWS*STATE;               // NROWS*STATE bf16

    a_kernel<<<dim3(STATE), dim3(STATE), 0, stream>>>(U, V, Atb16);
    prep_weights<<<dim3(256, 4), dim3(256), 0, stream>>>(in_w, B_w, gate_w, out_w,
                                                         in_wb, B_wb, gate_wb, out_wb);
    gemm_inB<<<dim3(NROWS/64), dim3(256), 0, stream>>>(x, in_wb, in_b, B_wb, B_b, state_out, bxu);
    scan_mfma<<<dim3(128), dim3(256), 0, stream>>>(bxu, Atb16, ylr, yrl);
    conv_combine<<<dim3(LSEQ/8, NBATCH), dim3(128), 0, stream>>>(ylr, yrl, conv_w, conv_b, ub);
    fused_out<<<dim3(NROWS/32), dim3(256), 0, stream>>>(x, ub, out_wb, out_b, gate_wb, gate_b,
                                                        norm_g, norm_b, yfinal);
    (void)in_sizes; (void)n_in; (void)out_size; (void)ws_size;
}

// Round 7
// 150.787 us; speedup vs baseline: 5.3821x; 1.0487x over previous
//
#include <hip/hip_runtime.h>
#include <hip/hip_bf16.h>

#define DIMC 256
#define STATE 128
#define RANK 64
#define NBATCH 16
#define LSEQ 4096
#define NROWS (NBATCH*LSEQ)   // 65536
#define LN_EPS 1e-5f
#define XSTR 264              // LDS row stride (bf16 elems) for staged x tiles
#define X1STR 136             // LDS row stride for x1 transpose tile

typedef __attribute__((ext_vector_type(8))) short frag8;   // 8 bf16 (4 VGPRs)
typedef __attribute__((ext_vector_type(4))) float f32x4;   // 4 fp32

union Pack4 { __hip_bfloat16 h[4]; uint2 u; };
union Pack8 { __hip_bfloat16 h[8]; uint4 u; };

__device__ inline void gload_lds16(const void* g, void* l) {
    __builtin_amdgcn_global_load_lds((const __attribute__((address_space(1))) void*)g,
                                     (__attribute__((address_space(3))) void*)l, 16, 0, 0);
}

// Stage a [NROWSW][32-k] bf16 weight slice into LDS linear [row][64B] via global_load_lds.
// Global source pre-swizzled (col ^= (row>>1)&3) so b128 frag reads spread banks.
template<int NROWSW, int NTHR>
__device__ inline void stage_wslice(const __hip_bfloat16* __restrict__ W, int Krow, int k0,
                                    __hip_bfloat16* dst, int t) {
    constexpr int ROUNDS = (NROWSW*64) / (NTHR*16);
    const int lane = t & 63, w = t >> 6;
    #pragma unroll
    for (int j = 0; j < ROUNDS; ++j) {
        int base = (w*ROUNDS + j) << 10;       // wave-uniform byte base in slice
        int X = base + lane*16;
        int r = X >> 6;
        int cg = (X >> 4) & 3;
        const __hip_bfloat16* src = W + (size_t)r*Krow + k0 + ((cg ^ ((r>>1)&3)) << 3);
        gload_lds16(src, (char*)dst + base);
    }
}
__device__ inline frag8 ld_wfrag(const __hip_bfloat16* buf, int row, int q) {
    return *(const frag8*)((const char*)buf + (row<<6) + ((q ^ ((row>>1)&3))<<4));
}

// ---------------- At[j][i] = A[i][j] = sum_r V[i,r]*U[j,r], stored bf16 ----------------
__global__ __launch_bounds__(128) void a_kernel(const float* __restrict__ U, const float* __restrict__ V,
                                                __hip_bfloat16* __restrict__ At) {
    int i = blockIdx.x, j = threadIdx.x;
    float s = 0.f;
    #pragma unroll
    for (int r = 0; r < RANK; ++r) s += V[i*RANK + r] * U[j*RANK + r];
    At[j*STATE + i] = __float2bfloat16(s);
}

// ---------------- weights fp32 -> bf16 ----------------
__global__ __launch_bounds__(256) void prep_weights(const float* __restrict__ in_w, const float* __restrict__ B_w,
                                                    const float* __restrict__ gate_w, const float* __restrict__ out_w,
                                                    __hip_bfloat16* __restrict__ in_wb, __hip_bfloat16* __restrict__ B_wb,
                                                    __hip_bfloat16* __restrict__ gate_wb, __hip_bfloat16* __restrict__ out_wb) {
    int idx = blockIdx.x*256 + threadIdx.x;
    int which = blockIdx.y;
    if (which == 0) { if (idx < STATE*DIMC)  in_wb[idx]   = __float2bfloat16(in_w[idx]); }
    else if (which == 1) { if (idx < STATE*STATE) B_wb[idx] = __float2bfloat16(B_w[idx]); }
    else if (which == 2) { if (idx < DIMC*DIMC)  gate_wb[idx] = __float2bfloat16(gate_w[idx]); }
    else { if (idx < DIMC*STATE) out_wb[idx] = __float2bfloat16(out_w[idx]); }
}

// ---- stage x[b][0..255][l0..l0+64) into LDS bf16 [l][cin^((l&3)<<3)], stride XSTR ----
// 1024 units of (4ch x 4l); per unit: 4x float4 coalesced loads -> in-reg transpose -> 4x ds_write_b64
template<int NTHR>
__device__ inline void stage_x64(const float* __restrict__ xb, int l0,
                                 __hip_bfloat16* __restrict__ xs, int t) {
    constexpr int UN = 1024 / NTHR;
    #pragma unroll
    for (int uu = 0; uu < UN; ++uu) {
        int unit = t + uu*NTHR;
        int lg = unit & 15, cg = unit >> 4;    // cg 0..63, lg 0..15
        int l = lg*4;
        float4 v0 = *(const float4*)(xb + (size_t)(cg*4+0)*LSEQ + l0 + l);
        float4 v1 = *(const float4*)(xb + (size_t)(cg*4+1)*LSEQ + l0 + l);
        float4 v2 = *(const float4*)(xb + (size_t)(cg*4+2)*LSEQ + l0 + l);
        float4 v3 = *(const float4*)(xb + (size_t)(cg*4+3)*LSEQ + l0 + l);
        const float* p0 = (const float*)&v0; const float* p1 = (const float*)&v1;
        const float* p2 = (const float*)&v2; const float* p3 = (const float*)&v3;
        #pragma unroll
        for (int li = 0; li < 4; ++li) {
            Pack4 p;
            p.h[0] = __float2bfloat16(p0[li]);
            p.h[1] = __float2bfloat16(p1[li]);
            p.h[2] = __float2bfloat16(p2[li]);
            p.h[3] = __float2bfloat16(p3[li]);
            int row = l + li;
            int col = (cg*4) ^ ((row&3)<<3);
            *(uint2*)(xs + (size_t)row*XSTR + col) = p.u;
        }
    }
}
__device__ inline frag8 ld_xfrag(const __hip_bfloat16* __restrict__ xs, int row, int k) {
    return *(const frag8*)(xs + (size_t)row*XSTR + (k ^ ((row&3)<<3)));
}

// ---------------- fused in_proj + B GEMM with LDS-staged dbuf weights ----------------
// block = 64 l rows, 512 threads = 8 waves in 4(M) x 2(N).
__global__ __launch_bounds__(512) void gemm_inB(const float* __restrict__ x,
                                                const __hip_bfloat16* __restrict__ in_wb, const float* __restrict__ in_b,
                                                const __hip_bfloat16* __restrict__ B_wb, const float* __restrict__ B_b,
                                                float* __restrict__ state_out, float* __restrict__ bx) {
    __shared__ __hip_bfloat16 xs[64*XSTR];                  // 33792 B; x1s aliases after GEMM1
    __shared__ __hip_bfloat16 wsl[2][4096];                 // 2 x 8192 B weight slices
    __hip_bfloat16* x1s = xs;
    const int t = threadIdx.x;
    const int lane = t & 63;
    const int c = lane & 15, q = lane >> 4;
    const int w = t >> 6, wm = w >> 1, wc = w & 1;
    const int r0 = blockIdx.x * 64;
    const int b = r0 >> 12, l0 = r0 & 4095;

    stage_x64<512>(x + (size_t)b*DIMC*LSEQ, l0, xs, t);
    stage_wslice<STATE,512>(in_wb, DIMC, 0, wsl[0], t);
    __syncthreads();

    // GEMM 1: x1[l][s] = sum_c x*W_in  (8 k-slices, dbuf)
    f32x4 acc[4] = {};
    #pragma unroll
    for (int i = 0; i < 8; ++i) {
        if (i < 7) stage_wslice<STATE,512>(in_wb, DIMC, (i+1)*32, wsl[(i+1)&1], t);
        frag8 af = ld_xfrag(xs, wm*16 + c, i*32 + q*8);
        #pragma unroll
        for (int nt = 0; nt < 4; ++nt) {
            frag8 bf = ld_wfrag(wsl[i&1], wc*64 + nt*16 + c, q);
            acc[nt] = __builtin_amdgcn_mfma_f32_16x16x32_bf16(af, bf, acc[nt], 0, 0, 0);
        }
        __syncthreads();
    }

    stage_wslice<STATE,512>(B_wb, STATE, 0, wsl[0], t);   // prologue for GEMM2

    // emit x1: fp32 -> state_out, bf16 -> swizzled LDS transpose
    #pragma unroll
    for (int nt = 0; nt < 4; ++nt) {
        int col = wc*64 + nt*16 + c;
        float bb = in_b[col];
        #pragma unroll
        for (int r = 0; r < 4; ++r) {
            int row = wm*16 + q*4 + r;
            float v = acc[nt][r] + bb;
            state_out[(size_t)(r0 + row)*STATE + col] = v;
            x1s[(size_t)row*X1STR + (col ^ ((row&3)<<3))] = __float2bfloat16(v);
        }
    }
    __syncthreads();

    // GEMM 2: bx[l][s'] = sum_s x1*B_w  (4 k-slices, dbuf)
    f32x4 acc2[4] = {};
    #pragma unroll
    for (int i = 0; i < 4; ++i) {
        if (i < 3) stage_wslice<STATE,512>(B_wb, STATE, (i+1)*32, wsl[(i+1)&1], t);
        int row = wm*16 + c;
        frag8 af = *(const frag8*)(x1s + (size_t)row*X1STR + (((i*32) + q*8) ^ ((row&3)<<3)));
        #pragma unroll
        for (int nt = 0; nt < 4; ++nt) {
            frag8 bf = ld_wfrag(wsl[i&1], wc*64 + nt*16 + c, q);
            acc2[nt] = __builtin_amdgcn_mfma_f32_16x16x32_bf16(af, bf, acc2[nt], 0, 0, 0);
        }
        __syncthreads();
    }
    const int orow = r0 + wm*16 + q*4;
    #pragma unroll
    for (int nt = 0; nt < 4; ++nt) {
        int col = wc*64 + nt*16 + c;
        float bb = B_b[col];
        #pragma unroll
        for (int r = 0; r < 4; ++r)
            bx[(size_t)(orow + r)*STATE + col] = acc2[nt][r] + bb;
    }
}

// ---------------- MFMA batched scan: 16 scans/block, 4 waves (32 state rows each) ----------------
#define HSTRIDE 144
__global__ __launch_bounds__(256, 1) void scan_mfma(const float* __restrict__ bx,
                                                    const __hip_bfloat16* __restrict__ At,
                                                    __hip_bfloat16* __restrict__ ylr,
                                                    __hip_bfloat16* __restrict__ yrl) {
    __shared__ __hip_bfloat16 Hb[16 * HSTRIDE];
    const int t = threadIdx.x;
    const int l = t & 63;
    const int wm = t >> 6;
    const int c = l & 15;
    const int q = l >> 4;

    const int S   = blockIdx.x * 16 + c;
    const int dir = S >> 10;
    const int b   = (S >> 6) & 15;
    const int blk = S & 63;
    const int lp0 = blk * 64;
    const int lorig0 = dir ? (LSEQ - 1 - lp0) : lp0;
    const int sgnstep = dir ? -STATE : STATE;

    const float* bxrow = bx + ((size_t)b*LSEQ + lorig0)*STATE;
    __hip_bfloat16* yrow = (dir ? yrl : ylr) + ((size_t)b*LSEQ + lp0)*STATE;

    frag8 afr[2][4];
    #pragma unroll
    for (int mm = 0; mm < 2; ++mm)
        #pragma unroll
        for (int kc = 0; kc < 4; ++kc)
            afr[mm][kc] = *(const frag8*)(At + (size_t)((wm*2+mm)*16 + c)*STATE + kc*32 + q*8);

    for (int k = t; k < 16*HSTRIDE; k += 256) Hb[k] = __float2bfloat16(0.f);
    __syncthreads();

    f32x4 pf[2];
    #pragma unroll
    for (int mm = 0; mm < 2; ++mm)
        pf[mm] = *(const f32x4*)(bxrow + (wm*2+mm)*16 + q*4);

    for (int tt = 0; tt < 64; ++tt) {
        frag8 bfr[4];
        #pragma unroll
        for (int kc = 0; kc < 4; ++kc)
            bfr[kc] = *(const frag8*)(&Hb[c*HSTRIDE + kc*32 + q*8]);

        f32x4 acc[2];
        #pragma unroll
        for (int mm = 0; mm < 2; ++mm) {
            f32x4 a = {0.f, 0.f, 0.f, 0.f};
            #pragma unroll
            for (int kc = 0; kc < 4; ++kc)
                a = __builtin_amdgcn_mfma_f32_16x16x32_bf16(afr[mm][kc], bfr[kc], a, 0, 0, 0);
            acc[mm] = a + pf[mm];
        }
        if (tt < 63) {
            bxrow += sgnstep;
            #pragma unroll
            for (int mm = 0; mm < 2; ++mm)
                pf[mm] = *(const f32x4*)(bxrow + (wm*2+mm)*16 + q*4);
        }

        Pack4 pk[2];
        #pragma unroll
        for (int mm = 0; mm < 2; ++mm) {
            pk[mm].h[0] = __float2bfloat16(acc[mm][0]);
            pk[mm].h[1] = __float2bfloat16(acc[mm][1]);
            pk[mm].h[2] = __float2bfloat16(acc[mm][2]);
            pk[mm].h[3] = __float2bfloat16(acc[mm][3]);
        }
        #pragma unroll
        for (int mm = 0; mm < 2; ++mm)
            *(uint2*)(yrow + (wm*2+mm)*16 + q*4) = pk[mm].u;
        yrow += STATE;

        __syncthreads();
        #pragma unroll
        for (int mm = 0; mm < 2; ++mm)
            *(uint2*)(&Hb[c*HSTRIDE + (wm*2+mm)*16 + q*4]) = pk[mm].u;
        __syncthreads();
    }
}

// ---------------- conv7 + combine: u = 0.5*(conv(ylr)+rev(conv(yrl))) + conv_b, bf16 io ----------------
__global__ __launch_bounds__(128) void conv_combine(const __hip_bfloat16* __restrict__ ylr,
                                                    const __hip_bfloat16* __restrict__ yrl,
                                                    const float* __restrict__ conv_w, const float* __restrict__ conv_b,
                                                    __hip_bfloat16* __restrict__ u) {
    const int t = threadIdx.x;
    const int s8 = (t & 15) * 8;
    const int l = blockIdx.x * 8 + (t >> 4);
    const int b = blockIdx.y;

    float wv[8][7];
    #pragma unroll
    for (int j = 0; j < 8; ++j)
        #pragma unroll
        for (int i = 0; i < 7; ++i) wv[j][i] = conv_w[(s8+j)*7 + i];

    const __hip_bfloat16* plr = ylr + (size_t)b*LSEQ*STATE;
    const __hip_bfloat16* prl = yrl + (size_t)b*LSEQ*STATE;

    float acc[8];
    {
        Pack8 v; v.u = *(const uint4*)(plr + (size_t)l*STATE + s8);
        #pragma unroll
        for (int j = 0; j < 8; ++j) acc[j] = __bfloat162float(v.h[j]);
    }
    #pragma unroll
    for (int i = 0; i < 7; ++i) {
        int qq = l - 3 + i;
        if (qq >= 0 && qq < LSEQ) {
            Pack8 v; v.u = *(const uint4*)(plr + (size_t)qq*STATE + s8);
            #pragma unroll
            for (int j = 0; j < 8; ++j) acc[j] += wv[j][i] * __bfloat162float(v.h[j]);
        }
    }
    const int lp = LSEQ - 1 - l;
    {
        Pack8 v; v.u = *(const uint4*)(prl + (size_t)lp*STATE + s8);
        #pragma unroll
        for (int j = 0; j < 8; ++j) acc[j] += __bfloat162float(v.h[j]);
    }
    #pragma unroll
    for (int i = 0; i < 7; ++i) {
        int qq = lp - 3 + i;
        if (qq >= 0 && qq < LSEQ) {
            Pack8 v; v.u = *(const uint4*)(prl + (size_t)qq*STATE + s8);
            #pragma unroll
            for (int j = 0; j < 8; ++j) acc[j] += wv[j][i] * __bfloat162float(v.h[j]);
        }
    }
    Pack8 o;
    #pragma unroll
    for (int j = 0; j < 8; ++j) o.h[j] = __float2bfloat16(0.5f*acc[j] + conv_b[s8+j]);
    *(uint4*)(u + ((size_t)b*LSEQ + l)*STATE + s8) = o.u;
}

// ---------------- fused MFMA: gate+out GEMM (LDS-staged dbuf weights) + epilogue ----------------
// block = 64 l x 256 c; 512 threads = 8 waves in 4(M) x 2(N).
__global__ __launch_bounds__(512) void fused_out(const float* __restrict__ x, const __hip_bfloat16* __restrict__ ub,
    const __hip_bfloat16* __restrict__ out_wb, const float* __restrict__ out_b,
    const __hip_bfloat16* __restrict__ gate_wb, const float* __restrict__ gate_b,
    const float* __restrict__ norm_g, const float* __restrict__ norm_b,
    float* __restrict__ y) {
    __shared__ __hip_bfloat16 xs[64*XSTR];         // 33792 B
    __shared__ __hip_bfloat16 wsl[2][8192];        // 2 x 16384 B weight slices (256 rows)
    __shared__ float lnbuf[4][2][16][2];
    const int t = threadIdx.x;
    const int lane = t & 63, c = lane & 15, q = lane >> 4;
    const int w = t >> 6, wm = w >> 1, wc = w & 1;
    const int r0 = blockIdx.x * 64;
    const int b = r0 >> 12, l0 = r0 & 4095;

    stage_x64<512>(x + (size_t)b*DIMC*LSEQ, l0, xs, t);
    // u A-frags prefetched to registers (latency hidden under gate GEMM)
    frag8 ufr[4];
    {
        const int arow = r0 + wm*16 + c;
        #pragma unroll
        for (int kc = 0; kc < 4; ++kc)
            ufr[kc] = *(const frag8*)(ub + (size_t)arow*STATE + kc*32 + q*8);
    }
    stage_wslice<DIMC,512>(gate_wb, DIMC, 0, wsl[0], t);
    __syncthreads();

    f32x4 accg[8] = {};
    f32x4 acco[8] = {};
    #pragma unroll
    for (int i = 0; i < 12; ++i) {
        if (i < 11) {
            if (i < 7) stage_wslice<DIMC,512>(gate_wb, DIMC, (i+1)*32, wsl[(i+1)&1], t);
            else       stage_wslice<DIMC,512>(out_wb,  STATE, (i-7)*32, wsl[(i+1)&1], t);
        }
        if (i < 8) {
            frag8 af = ld_xfrag(xs, wm*16 + c, i*32 + q*8);
            #pragma unroll
            for (int nt = 0; nt < 8; ++nt) {
                frag8 bf = ld_wfrag(wsl[i&1], wc*128 + nt*16 + c, q);
                accg[nt] = __builtin_amdgcn_mfma_f32_16x16x32_bf16(af, bf, accg[nt], 0, 0, 0);
            }
        } else {
            frag8 af = ufr[i-8];
            #pragma unroll
            for (int nt = 0; nt < 8; ++nt) {
                frag8 bf = ld_wfrag(wsl[i&1], wc*128 + nt*16 + c, q);
                acco[nt] = __builtin_amdgcn_mfma_f32_16x16x32_bf16(af, bf, acco[nt], 0, 0, 0);
            }
        }
        __syncthreads();
    }

    // epilogue in registers: v = sigmoid(gate)*o + residual(from xs); LN partials
    float s1[4] = {0.f,0.f,0.f,0.f}, s2[4] = {0.f,0.f,0.f,0.f};
    #pragma unroll
    for (int nt = 0; nt < 8; ++nt) {
        int col = wc*128 + nt*16 + c;
        float gb = gate_b[col], ob = out_b[col];
        #pragma unroll
        for (int r = 0; r < 4; ++r) {
            int row = wm*16 + q*4 + r;
            float res = __bfloat162float(xs[(size_t)row*XSTR + (col ^ ((row&3)<<3))]);
            float g = 1.f/(1.f + expf(-(accg[nt][r] + gb)));
            float v = g*(acco[nt][r] + ob) + res;
            accg[nt][r] = v;
            s1[r] += v; s2[r] += v*v;
        }
    }
    #pragma unroll
    for (int m = 1; m <= 8; m <<= 1) {
        #pragma unroll
        for (int r = 0; r < 4; ++r) {
            s1[r] += __shfl_xor(s1[r], m);
            s2[r] += __shfl_xor(s2[r], m);
        }
    }
    if (c == 0) {
        #pragma unroll
        for (int r = 0; r < 4; ++r) {
            lnbuf[wm][wc][q*4 + r][0] = s1[r];
            lnbuf[wm][wc][q*4 + r][1] = s2[r];
        }
    }
    __syncthreads();
    float mu[4], rstd[4];
    #pragma unroll
    for (int r = 0; r < 4; ++r) {
        int row16 = q*4 + r;
        float t1 = lnbuf[wm][0][row16][0] + lnbuf[wm][1][row16][0];
        float t2 = lnbuf[wm][0][row16][1] + lnbuf[wm][1][row16][1];
        float m_ = t1 * (1.f/256.f);
        mu[r] = m_;
        rstd[r] = rsqrtf(t2 * (1.f/256.f) - m_*m_ + LN_EPS);
    }
    #pragma unroll
    for (int nt = 0; nt < 8; ++nt) {
        int col = wc*128 + nt*16 + c;
        float g = norm_g[col], be = norm_b[col];
        float4 v4;
        v4.x = (accg[nt][0] - mu[0]) * rstd[0] * g + be;
        v4.y = (accg[nt][1] - mu[1]) * rstd[1] * g + be;
        v4.z = (accg[nt][2] - mu[2]) * rstd[2] * g + be;
        v4.w = (accg[nt][3] - mu[3]) * rstd[3] * g + be;
        *(float4*)(y + ((size_t)b*DIMC + col)*LSEQ + l0 + wm*16 + q*4) = v4;
    }
}

extern "C" void kernel_launch(void* const* d_in, const int* in_sizes, int n_in,
                              void* d_out, int out_size, void* d_ws, size_t ws_size,
                              hipStream_t stream) {
    const float* x      = (const float*)d_in[0];
    const float* in_w   = (const float*)d_in[1];
    const float* in_b   = (const float*)d_in[2];
    const float* U      = (const float*)d_in[3];
    const float* V      = (const float*)d_in[4];
    const float* B_w    = (const float*)d_in[5];
    const float* B_b    = (const float*)d_in[6];
    const float* out_w  = (const float*)d_in[7];
    const float* out_b  = (const float*)d_in[8];
    const float* gate_w = (const float*)d_in[9];
    const float* gate_b = (const float*)d_in[10];
    const float* norm_g = (const float*)d_in[11];
    const float* norm_b = (const float*)d_in[12];
    const float* conv_w = (const float*)d_in[13];
    const float* conv_b = (const float*)d_in[14];

    float* yfinal = (float*)d_out;                                 // [16][256][64][64]
    float* state_out = yfinal + (size_t)NBATCH*DIMC*LSEQ;          // [16][4096][128] fp32

    float* ws  = (float*)d_ws;
    float* bxu = ws;                                               // bx fp32; later u bf16
    __hip_bfloat16* ub = (__hip_bfloat16*)ws;
    __hip_bfloat16* Atb16  = (__hip_bfloat16*)(ws + (size_t)NROWS*STATE);
    __hip_bfloat16* in_wb  = Atb16 + STATE*STATE;
    __hip_bfloat16* B_wb   = in_wb + STATE*DIMC;
    __hip_bfloat16* gate_wb= B_wb + STATE*STATE;
    __hip_bfloat16* out_wb = gate_wb + DIMC*DIMC;

    // bf16 scan outputs live in the (later overwritten) y region of d_out
    __hip_bfloat16* ylr = (__hip_bfloat16*)yfinal;                 // NROWS*STATE bf16
    __hip_bfloat16* yrl = ylr + (size_t)NROWS*STATE;               // NROWS*STATE bf16

    a_kernel<<<dim3(STATE), dim3(STATE), 0, stream>>>(U, V, Atb16);
    prep_weights<<<dim3(256, 4), dim3(256), 0, stream>>>(in_w, B_w, gate_w, out_w,
                                                         in_wb, B_wb, gate_wb, out_wb);
    gemm_inB<<<dim3(NROWS/64), dim3(512), 0, stream>>>(x, in_wb, in_b, B_wb, B_b, state_out, bxu);
    scan_mfma<<<dim3(128), dim3(256), 0, stream>>>(bxu, Atb16, ylr, yrl);
    conv_combine<<<dim3(LSEQ/8, NBATCH), dim3(128), 0, stream>>>(ylr, yrl, conv_w, conv_b, ub);
    fused_out<<<dim3(NROWS/64), dim3(512), 0, stream>>>(x, ub, out_wb, out_b, gate_wb, gate_b,
                                                        norm_g, norm_b, yfinal);
    (void)in_sizes; (void)n_in; (void)out_size; (void)ws_size;
}